// Round 4
// baseline (583.847 us; speedup 1.0000x reference)
//
#include <hip/hip_runtime.h>

// Problem constants
#define F_DIMC 1024
#define HIDC   4096
#define NH     16
#define SEQ    2048
#define BATCH  4
#define ROWS   (BATCH * SEQ)                    // 8192
#define MEG    (1u << 20)
#define QSCALE 0.18033688011112042f             // 0.125 * log2(e)

typedef unsigned short u16t;
typedef __attribute__((ext_vector_type(8))) short short8;   // 8 bf16 (4 VGPRs) — MFMA A/B frag
typedef __attribute__((ext_vector_type(4))) float floatx4;  // MFMA C/D frag
typedef __attribute__((address_space(1))) void gvoid_t;
typedef __attribute__((address_space(3))) void lvoid_t;
#define ASYNC16(g, l) __builtin_amdgcn_global_load_lds((gvoid_t*)(g), (lvoid_t*)(l), 16, 0, 0)

#if __has_builtin(__builtin_amdgcn_exp2f)
#define EXP2(x) __builtin_amdgcn_exp2f(x)       // raw v_exp_f32 (1 trans op)
#else
#define EXP2(x) exp2f(x)
#endif

__device__ __forceinline__ u16t f2bf(float f) {           // RNE float->bf16
    union { float f; unsigned u; } v; v.f = f;
    unsigned r = v.u + 0x7fffu + ((v.u >> 16) & 1u);
    return (u16t)(r >> 16);
}
__device__ __forceinline__ unsigned fasu(float f) {
    union { float f; unsigned u; } v; v.f = f; return v.u;
}

// ---------------------------------------------------------------------------
// LayerNorm: one 256-thread block per row of 1024 floats; bf16 output.
// ---------------------------------------------------------------------------
__global__ __launch_bounds__(256) void ln_kernel(const float* __restrict__ x,
                                                 const float* __restrict__ w,
                                                 const float* __restrict__ b,
                                                 u16t* __restrict__ out) {
    const int row = blockIdx.x;
    const int t = threadIdx.x;
    const float* xp = x + (size_t)row * F_DIMC;

    float4 v = *(const float4*)(xp + t * 4);
    float s  = v.x + v.y + v.z + v.w;
    float ss = v.x * v.x + v.y * v.y + v.z * v.z + v.w * v.w;
    for (int off = 32; off; off >>= 1) {
        s  += __shfl_down(s, off);
        ss += __shfl_down(ss, off);
    }
    __shared__ float red[8];
    const int wid = t >> 6, lid = t & 63;
    if (lid == 0) { red[wid] = s; red[4 + wid] = ss; }
    __syncthreads();
    if (t == 0) {
        float S  = red[0] + red[1] + red[2] + red[3];
        float SS = red[4] + red[5] + red[6] + red[7];
        float mu  = S * (1.0f / F_DIMC);
        float var = SS * (1.0f / F_DIMC) - mu * mu;
        red[0] = mu;
        red[1] = rsqrtf(var + 1e-6f);
    }
    __syncthreads();
    const float mu = red[0], rs = red[1];

    float4 wv = *(const float4*)(w + t * 4);
    float4 bv = *(const float4*)(b + t * 4);
    ushort4 o = make_ushort4(f2bf((v.x - mu) * rs * wv.x + bv.x),
                             f2bf((v.y - mu) * rs * wv.y + bv.y),
                             f2bf((v.z - mu) * rs * wv.z + bv.z),
                             f2bf((v.w - mu) * rs * wv.w + bv.w));
    *(ushort4*)(out + (size_t)row * F_DIMC + t * 4) = o;
}

// ---------------------------------------------------------------------------
// Weight conversion fp32 -> bf16, all 6 matrices in one launch.
// wbuf layout: wq[0,1M) wk[1M,2M) wv[2M,3M) fc[3M,4M) fc1[4M,8M) fc2[8M,12M)
// ---------------------------------------------------------------------------
__global__ __launch_bounds__(256) void wconv_kernel(const float* __restrict__ w0,
        const float* __restrict__ w1, const float* __restrict__ w2,
        const float* __restrict__ w3, const float* __restrict__ w4,
        const float* __restrict__ w5, u16t* __restrict__ dst) {
    const size_t e = ((size_t)blockIdx.x * 256 + threadIdx.x) * 4;
    const float* src; size_t off;
    if      (e < 1 * MEG) { src = w0; off = e; }
    else if (e < 2 * MEG) { src = w1; off = e - 1 * MEG; }
    else if (e < 3 * MEG) { src = w2; off = e - 2 * MEG; }
    else if (e < 4 * MEG) { src = w3; off = e - 3 * MEG; }
    else if (e < 8 * MEG) { src = w4; off = e - 4 * MEG; }
    else                  { src = w5; off = e - 8 * MEG; }
    float4 f = *(const float4*)(src + off);
    *(ushort4*)(dst + e) = make_ushort4(f2bf(f.x), f2bf(f.y), f2bf(f.z), f2bf(f.w));
}

// ---------------------------------------------------------------------------
// 8-phase 256x256 GEMM core, v2 (m201-faithful; correct-by-construction).
// BM=BN=256, BK=64, 512 threads = 8 waves as 2(M wr) x 4(N wc);
// per-wave output 128x64 = acc[8][4]. LDS = A[2][2half][128][64] +
// B[2][2half][128][64] = 128 KiB. Parity: even K-tiles -> buf0, odd -> buf1.
// 16B-blocks XOR-swizzled (phys = logical ^ (row&7)); global_load_lds dest
// linear, SOURCE pre-swizzled (rule 21); ds_reads undo the XOR.
//
// Iteration u consumes tiles U=2u (ph0-3) and U+1 (ph4-7).
// Region last-read map (per phase, derived from quadrant schedule):
//   A(U)h0/h1: ph2   B(U)h0/h1: ph1   A(U+1)h0/h1: ph6   B(U+1)h0/h1: ph5
// Stage stream (1 half-tile = 2 loads per phase; each stage >=1 barrier
// after its region's last read):
//   ph0: A(U+1)h1   ph1: B(U+1)h1   ph2: B(U+2)h0   ph3: A(U+2)h0
//   ph4: A(U+2)h1   ph5: B(U+2)h1   ph6: B(U+3)h0   ph7: A(U+3)h0
// vmcnt(4) after MFMA at ph3 (certifies tile U+1 complete: keeps newest 4 =
// ph2+ph3 stages) and ph7 (certifies tile U+2: keeps ph6+ph7). Carried
// across iterations: {B(U+3)h0, A(U+3)h0} — matches prologue tail.
// Per-phase skeleton: reads | stage | barrier | setprio(1) 16xMFMA
// setprio(0) | [vmcnt] | barrier.  NO sched_barrier(0) (m141: pinning kills).
// ---------------------------------------------------------------------------
#define MFMA_Q(ACCM, ACCN, FA, FB)                                             \
    _Pragma("unroll")                                                          \
    for (int mi = 0; mi < 4; ++mi)                                             \
        _Pragma("unroll")                                                      \
        for (int ni = 0; ni < 2; ++ni) {                                       \
            acc[(ACCM) + mi][(ACCN) + ni] =                                    \
                __builtin_amdgcn_mfma_f32_16x16x32_bf16(                       \
                    FA[mi][0], FB[ni][0], acc[(ACCM) + mi][(ACCN) + ni], 0, 0, 0); \
            acc[(ACCM) + mi][(ACCN) + ni] =                                    \
                __builtin_amdgcn_mfma_f32_16x16x32_bf16(                       \
                    FA[mi][1], FB[ni][1], acc[(ACCM) + mi][(ACCN) + ni], 0, 0, 0); \
        }

#define STAGE_A(par, h, kt) do {                                               \
        u16t* d_ = &As[par][(h) * 8192];                                       \
        ASYNC16(aP0 + (h) * aH + (size_t)(kt) * 64, d_ + l0);                  \
        ASYNC16(aP1 + (h) * aH + (size_t)(kt) * 64, d_ + l1); } while (0)
#define STAGE_B(par, h, kt) do {                                               \
        u16t* d_ = &Bs[par][(h) * 8192];                                       \
        ASYNC16(bP0 + (h) * aH + (size_t)(kt) * 64, d_ + l0);                  \
        ASYNC16(bP1 + (h) * aH + (size_t)(kt) * 64, d_ + l1); } while (0)
#define VMCNT4 asm volatile("s_waitcnt vmcnt(4)" ::: "memory")
#define VMCNT0 asm volatile("s_waitcnt vmcnt(0)" ::: "memory")
#define BAR()  __builtin_amdgcn_s_barrier()
#define PRIO1() __builtin_amdgcn_s_setprio(1)
#define PRIO0() __builtin_amdgcn_s_setprio(0)

#define DP8_CORE(Aq, Wq, Kdim)                                                 \
    __shared__ u16t As[2][2 * 8192] __attribute__((aligned(16)));              \
    __shared__ u16t Bs[2][2 * 8192] __attribute__((aligned(16)));              \
    const int t = threadIdx.x;                                                 \
    const int lane = t & 63;                                                   \
    const int wave = t >> 6;                                                   \
    const int wr = wave >> 2, wc = wave & 3;                                   \
    const int fm = lane & 15, fq = lane >> 4;                                  \
    const int nwg = gridDim.x;                                                 \
    const int swzb = (blockIdx.x & 7) * (nwg >> 3) + (blockIdx.x >> 3);        \
    const int m0 = (swzb & 31) * 256;          /* 32 m-blocks (M=8192) */      \
    const int n0 = (swzb >> 5) * 256;                                          \
    /* staging: thread covers 16B-blocks beta0, beta1 of each 16KB half;       \
       source k-block j = (beta&7)^(row&7) — the involution reads undo */      \
    const int beta0 = t, beta1 = t + 512;                                      \
    const int r0 = beta0 >> 3, j0 = (beta0 & 7) ^ (r0 & 7);                    \
    const int r1 = beta1 >> 3, j1 = (beta1 & 7) ^ (r1 & 7);                    \
    const u16t* aP0 = (Aq) + (size_t)(m0 + r0) * (Kdim) + j0 * 8;              \
    const u16t* aP1 = (Aq) + (size_t)(m0 + r1) * (Kdim) + j1 * 8;              \
    const u16t* bP0 = (Wq) + (size_t)(n0 + r0) * (Kdim) + j0 * 8;              \
    const u16t* bP1 = (Wq) + (size_t)(n0 + r1) * (Kdim) + j1 * 8;              \
    const size_t aH = (size_t)128 * (Kdim);    /* half row-stride (elems) */   \
    const int l0 = beta0 * 8, l1 = beta1 * 8;                                  \
    /* frag read bases; XOR row term = fm&7 (mi/ni-invariant) */               \
    int aoff[2], boff[2];                                                      \
    _Pragma("unroll")                                                          \
    for (int ks = 0; ks < 2; ++ks) {                                           \
        const int sw = ((ks * 4 + fq) ^ (fm & 7)) * 8;                         \
        aoff[ks] = wr * 8192 + fm * 64 + sw;                                   \
        boff[ks] = (wc >> 1) * 8192 + ((wc & 1) * 64 + fm) * 64 + sw;          \
    }                                                                          \
    const int NT = (Kdim) / 64;                                                \
    /* prologue: tile0 (4 half-tiles) + {B1h0, A1h0}; vmcnt(4) keeps the      \
       latter two in flight == steady-state carried queue */                   \
    STAGE_A(0, 0, 0); STAGE_A(0, 1, 0); STAGE_B(0, 0, 0); STAGE_B(0, 1, 0);    \
    STAGE_B(1, 0, 1); STAGE_A(1, 0, 1);                                        \
    VMCNT4;                                                                    \
    BAR();                                                                     \
    floatx4 acc[8][4] = {};                                                    \
    short8 fa[4][2], fbL[2][2], fbH[2][2];                                     \
    for (int u = 0; u < NT / 2; ++u) {                                         \
        const int U = 2 * u;                                                   \
        const bool full = (U + 4 <= NT);                                       \
        const u16t* A0 = &As[0][0];  const u16t* B0 = &Bs[0][0];               \
        const u16t* A1 = &As[1][0];  const u16t* B1 = &Bs[1][0];               \
        /* -------- ph0: A(U)lo + B(U)lo reads; stage A(U+1)h1 -------- */     \
        _Pragma("unroll")                                                      \
        for (int mi = 0; mi < 4; ++mi) {                                       \
            fa[mi][0] = *(const short8*)(A0 + aoff[0] + mi * 1024);            \
            fa[mi][1] = *(const short8*)(A0 + aoff[1] + mi * 1024);            \
        }                                                                      \
        _Pragma("unroll")                                                      \
        for (int ni = 0; ni < 2; ++ni) {                                       \
            fbL[ni][0] = *(const short8*)(B0 + boff[0] + ni * 1024);           \
            fbL[ni][1] = *(const short8*)(B0 + boff[1] + ni * 1024);           \
        }                                                                      \
        STAGE_A(1, 1, U + 1);                                                  \
        BAR();                                                                 \
        PRIO1(); MFMA_Q(0, 0, fa, fbL) PRIO0();                                \
        BAR();                                                                 \
        /* -------- ph1: B(U)hi reads; stage B(U+1)h1 -------- */              \
        _Pragma("unroll")                                                      \
        for (int ni = 0; ni < 2; ++ni) {                                       \
            fbH[ni][0] = *(const short8*)(B0 + boff[0] + 2048 + ni * 1024);    \
            fbH[ni][1] = *(const short8*)(B0 + boff[1] + 2048 + ni * 1024);    \
        }                                                                      \
        STAGE_B(1, 1, U + 1);                                                  \
        BAR();                                                                 \
        PRIO1(); MFMA_Q(0, 2, fa, fbH) PRIO0();                                \
        BAR();                                                                 \
        /* -------- ph2: A(U)hi reads; stage B(U+2)h0 -------- */              \
        _Pragma("unroll")                                                      \
        for (int mi = 0; mi < 4; ++mi) {                                       \
            fa[mi][0] = *(const short8*)(A0 + aoff[0] + 4096 + mi * 1024);     \
            fa[mi][1] = *(const short8*)(A0 + aoff[1] + 4096 + mi * 1024);     \
        }                                                                      \
        if (full) STAGE_B(0, 0, U + 2);                                        \
        BAR();                                                                 \
        PRIO1(); MFMA_Q(4, 0, fa, fbL) PRIO0();                                \
        BAR();                                                                 \
        /* -------- ph3: stage A(U+2)h0; vmcnt certifies tile U+1 ---- */      \
        if (full) STAGE_A(0, 0, U + 2);                                        \
        BAR();                                                                 \
        PRIO1(); MFMA_Q(4, 2, fa, fbH) PRIO0();                                \
        if (full) { VMCNT4; } else { VMCNT0; }                                 \
        BAR();                                                                 \
        /* -------- ph4: A(U+1)lo + B(U+1)lo; stage A(U+2)h1 -------- */       \
        _Pragma("unroll")                                                      \
        for (int mi = 0; mi < 4; ++mi) {                                       \
            fa[mi][0] = *(const short8*)(A1 + aoff[0] + mi * 1024);            \
            fa[mi][1] = *(const short8*)(A1 + aoff[1] + mi * 1024);            \
        }                                                                      \
        _Pragma("unroll")                                                      \
        for (int ni = 0; ni < 2; ++ni) {                                       \
            fbL[ni][0] = *(const short8*)(B1 + boff[0] + ni * 1024);           \
            fbL[ni][1] = *(const short8*)(B1 + boff[1] + ni * 1024);           \
        }                                                                      \
        if (full) STAGE_A(0, 1, U + 2);                                        \
        BAR();                                                                 \
        PRIO1(); MFMA_Q(0, 0, fa, fbL) PRIO0();                                \
        BAR();                                                                 \
        /* -------- ph5: B(U+1)hi; stage B(U+2)h1 -------- */                  \
        _Pragma("unroll")                                                      \
        for (int ni = 0; ni < 2; ++ni) {                                       \
            fbH[ni][0] = *(const short8*)(B1 + boff[0] + 2048 + ni * 1024);    \
            fbH[ni][1] = *(const short8*)(B1 + boff[1] + 2048 + ni * 1024);    \
        }                                                                      \
        if (full) STAGE_B(0, 1, U + 2);                                        \
        BAR();                                                                 \
        PRIO1(); MFMA_Q(0, 2, fa, fbH) PRIO0();                                \
        BAR();                                                                 \
        /* -------- ph6: A(U+1)hi; stage B(U+3)h0 -------- */                  \
        _Pragma("unroll")                                                      \
        for (int mi = 0; mi < 4; ++mi) {                                       \
            fa[mi][0] = *(const short8*)(A1 + aoff[0] + 4096 + mi * 1024);     \
            fa[mi][1] = *(const short8*)(A1 + aoff[1] + 4096 + mi * 1024);     \
        }                                                                      \
        if (full) STAGE_B(1, 0, U + 3);                                        \
        BAR();                                                                 \
        PRIO1(); MFMA_Q(4, 0, fa, fbL) PRIO0();                                \
        BAR();                                                                 \
        /* -------- ph7: stage A(U+3)h0; vmcnt certifies tile U+2 ---- */      \
        if (full) STAGE_A(1, 0, U + 3);                                        \
        BAR();                                                                 \
        PRIO1(); MFMA_Q(4, 2, fa, fbH) PRIO0();                                \
        if (full) { VMCNT4; } else { VMCNT0; }                                 \
        BAR();                                                                 \
    }

// ---------------------------------------------------------------------------
// Generic bf16 MFMA GEMM: C = A @ W^T + bias (+ReLU)(+res)
// 1D grid = (M/256)*(N/256), 512 threads.
// ---------------------------------------------------------------------------
template <bool RELU, bool RES, bool BF16OUT>
__global__ __launch_bounds__(512, 2) void gemm_dp(const u16t* __restrict__ A,
                                                  const u16t* __restrict__ W,
                                                  const float* __restrict__ bias,
                                                  const float* res, void* Cout,
                                                  int N, int K) {
    DP8_CORE(A, W, K)
    // Epilogue. C/D layout: col=lane&15, row=(lane>>4)*4+reg  [m89/m91].
    float bl[4];
#pragma unroll
    for (int ni = 0; ni < 4; ++ni) bl[ni] = bias[n0 + wc * 64 + ni * 16 + fm];
#pragma unroll
    for (int mi = 0; mi < 8; ++mi) {
#pragma unroll
        for (int ni = 0; ni < 4; ++ni) {
            const int col = n0 + wc * 64 + ni * 16 + fm;
#pragma unroll
            for (int r = 0; r < 4; ++r) {
                const int row = m0 + wr * 128 + mi * 16 + fq * 4 + r;
                const size_t off = (size_t)row * N + col;
                float c = acc[mi][ni][r] + bl[ni];
                if (RELU) c = fmaxf(c, 0.0f);
                if (RES)  c += res[off];
                if (BF16OUT) ((u16t*)Cout)[off] = f2bf(c);
                else         ((float*)Cout)[off] = c;
            }
        }
    }
}

// ---------------------------------------------------------------------------
// Fused QKV GEMM: A = h [8192][1024], W = W_qkv [3072][1024].
// n0 multiple of 256 never straddles the q/k/v 1024-boundaries. Routes:
// q (scaled) -> qb, k -> kb, v -> vtb TRANSPOSED (vtb[d][token]).
// 1D grid = 32*(3072/256) = 384, 512 threads.
// ---------------------------------------------------------------------------
__global__ __launch_bounds__(512, 2) void gemm_qkv(const u16t* __restrict__ A,
        const u16t* __restrict__ W,
        const float* __restrict__ wq_b, const float* __restrict__ wk_b,
        const float* __restrict__ wv_b,
        u16t* __restrict__ qb, u16t* __restrict__ kb, u16t* __restrict__ vtb) {
    DP8_CORE(A, W, F_DIMC)
    const int which = n0 >> 10;                 // 0=q 1=k 2=v
    const int nb = n0 & 1023;
    const float* bias = which == 0 ? wq_b : which == 1 ? wk_b : wv_b;
    float bl[4];
#pragma unroll
    for (int ni = 0; ni < 4; ++ni) bl[ni] = bias[nb + wc * 64 + ni * 16 + fm];

    if (which == 2) {
        // v: transposed store, 4 consecutive tokens packed per ushort4
#pragma unroll
        for (int mi = 0; mi < 8; ++mi)
#pragma unroll
            for (int ni = 0; ni < 4; ++ni) {
                const int col = nb + wc * 64 + ni * 16 + fm;        // d index
                const int row0 = m0 + wr * 128 + mi * 16 + fq * 4;  // token
                ushort4 pk = make_ushort4(f2bf(acc[mi][ni][0] + bl[ni]),
                                          f2bf(acc[mi][ni][1] + bl[ni]),
                                          f2bf(acc[mi][ni][2] + bl[ni]),
                                          f2bf(acc[mi][ni][3] + bl[ni]));
                *(ushort4*)(vtb + (size_t)col * ROWS + row0) = pk;
            }
    } else {
        u16t* dst = (which == 0) ? qb : kb;
        const float sc2 = (which == 0) ? QSCALE : 1.0f;
#pragma unroll
        for (int mi = 0; mi < 8; ++mi)
#pragma unroll
            for (int ni = 0; ni < 4; ++ni) {
                const int col = nb + wc * 64 + ni * 16 + fm;
#pragma unroll
                for (int r = 0; r < 4; ++r) {
                    const int row = m0 + wr * 128 + mi * 16 + fq * 4 + r;
                    dst[(size_t)row * F_DIMC + col] = f2bf((acc[mi][ni][r] + bl[ni]) * sc2);
                }
            }
    }
}

// ---------------------------------------------------------------------------
// MFMA flash attention, v3 (unchanged this round).
// ---------------------------------------------------------------------------
__global__ __launch_bounds__(256, 4) void attn_mfma(const u16t* __restrict__ qb,
        const u16t* __restrict__ kbuf, const u16t* __restrict__ vtb,
        u16t* __restrict__ ab) {
    __shared__ u16t Kt[2][64 * 64] __attribute__((aligned(16)));   // 16 KB
    __shared__ u16t Vs[64 * 64] __attribute__((aligned(16)));      // 8 KB
    __shared__ u16t QP[128 * 64] __attribute__((aligned(16)));     // 16 KB

    const int t = threadIdx.x;
    const int lane = t & 63;
    const int wave = t >> 6;
    const int l15 = lane & 15, q4 = lane >> 4;
    const int q0 = blockIdx.x * 128;
    const int bh = blockIdx.y;
    const int b = bh >> 4, hh = bh & 15;

    // ---- stage Q (cooperative): 1024 16B-blocks, swizzled ----
#pragma unroll
    for (int c = 0; c < 4; ++c) {
        const int beta = c * 256 + t;
        const int r = beta >> 3, o = (beta & 7) ^ (r & 7);
        ASYNC16(qb + (size_t)(b * SEQ + q0 + r) * F_DIMC + hh * 64 + o * 8,
                QP + beta * 8);
    }
    const u16t* kg = kbuf + (size_t)(b * SEQ) * F_DIMC + hh * 64;
    const u16t* vg = vtb + (size_t)(hh * 64) * ROWS + b * SEQ;

    // per-thread staging coords (loop-invariant)
    const int sb0 = t, sb1 = t + 256;
    const int sr0 = sb0 >> 3, so0 = (sb0 & 7) ^ (sr0 & 7);
    const int sr1 = sb1 >> 3, so1 = (sb1 & 7) ^ (sr1 & 7);
    const u16t* kp0 = kg + (size_t)sr0 * F_DIMC + so0 * 8;
    const u16t* kp1 = kg + (size_t)sr1 * F_DIMC + so1 * 8;
    const u16t* vp0 = vg + (size_t)sr0 * ROWS + so0 * 8;
    const u16t* vp1 = vg + (size_t)sr1 * ROWS + so1 * 8;

    // ---- pre-stage K0 -> Kt[0], V0 -> Vs ----
    ASYNC16(kp0, Kt[0] + sb0 * 8);
    ASYNC16(kp1, Kt[0] + sb1 * 8);
    ASYNC16(vp0, Vs + sb0 * 8);
    ASYNC16(vp1, Vs + sb1 * 8);
    kp0 += 64 * F_DIMC; kp1 += 64 * F_DIMC; vp0 += 64; vp1 += 64;
    __syncthreads();                       // Q + tile0 resident

    // ---- Q B-frags (this wave's 32 rows) ----
    short8 fqr[2][2];
#pragma unroll
    for (int mt = 0; mt < 2; ++mt)
#pragma unroll
        for (int ks = 0; ks < 2; ++ks) {
            const int m = wave * 32 + mt * 16 + l15;
            const int oct = ks * 4 + q4;
            fqr[mt][ks] = *(const short8*)(QP + (m * 8 + (oct ^ (m & 7))) * 8);
        }
    // From here QP rows [wave*32, wave*32+32) are private to this wave (P).

    short8 ones;                           // bf16 1.0 broadcast (B operand)
#pragma unroll
    for (int i = 0; i < 8; ++i) ones[i] = (short)0x3F80;

    floatx4 oacc[2][4] = {};
    floatx4 lacc[2] = {};

    for (int it = 0; it < SEQ / 64; ++it) {
        // prefetch K(it+1) into the other K buffer
        if (it + 1 < SEQ / 64) {
            u16t* kd = Kt[(it + 1) & 1];
            ASYNC16(kp0, kd + sb0 * 8);
            ASYNC16(kp1, kd + sb1 * 8);
            kp0 += 64 * F_DIMC; kp1 += 64 * F_DIMC;
        }
        const u16t* kcur = Kt[it & 1];

        // ---- S^T = K @ Q^T : C rows = keys, cols = queries ----
        short8 fk[4][2];
#pragma unroll
        for (int nt = 0; nt < 4; ++nt)
#pragma unroll
            for (int ks = 0; ks < 2; ++ks) {
                const int kr = nt * 16 + l15;
                const int oct = ks * 4 + q4;
                fk[nt][ks] = *(const short8*)(kcur + (kr * 8 + (oct ^ (kr & 7))) * 8);
            }
        floatx4 st[2][4] = {};
#pragma unroll
        for (int mt = 0; mt < 2; ++mt)
#pragma unroll
            for (int nt = 0; nt < 4; ++nt) {
                st[mt][nt] = __builtin_amdgcn_mfma_f32_16x16x32_bf16(
                    fk[nt][0], fqr[mt][0], st[mt][nt], 0, 0, 0);
                st[mt][nt] = __builtin_amdgcn_mfma_f32_16x16x32_bf16(
                    fk[nt][1], fqr[mt][1], st[mt][nt], 0, 0, 0);
            }

        // ---- P = exp2(S^T), truncate-pack via v_perm, b64 writes (own rows)
#pragma unroll
        for (int mt = 0; mt < 2; ++mt)
#pragma unroll
            for (int nt = 0; nt < 4; ++nt) {
                const float p0 = EXP2(st[mt][nt][0]);
                const float p1 = EXP2(st[mt][nt][1]);
                const float p2 = EXP2(st[mt][nt][2]);
                const float p3 = EXP2(st[mt][nt][3]);
                const unsigned lo = __builtin_amdgcn_perm(fasu(p1), fasu(p0), 0x07060302u);
                const unsigned hi = __builtin_amdgcn_perm(fasu(p3), fasu(p2), 0x07060302u);
                const int m = wave * 32 + mt * 16 + l15;
                const int logb = nt * 2 + (q4 >> 1);       // 16B-block of k0
                *(uint2*)(QP + (m * 8 + (logb ^ (m & 7))) * 8 + (q4 & 1) * 4) =
                    make_uint2(lo, hi);
            }

        __syncthreads();   // B: drains V(it) (issued last iter) + K(it+1)

        // ---- O += P @ V ;  l += P @ 1 ----
        short8 fp[2][2], fv[4][2];
#pragma unroll
        for (int mt = 0; mt < 2; ++mt)
#pragma unroll
            for (int ks = 0; ks < 2; ++ks) {
                const int m = wave * 32 + mt * 16 + l15;
                const int oct = ks * 4 + q4;
                fp[mt][ks] = *(const short8*)(QP + (m * 8 + (oct ^ (m & 7))) * 8);
            }
#pragma unroll
        for (int nd = 0; nd < 4; ++nd)
#pragma unroll
            for (int ks = 0; ks < 2; ++ks) {
                const int d = nd * 16 + l15;
                const int oct = ks * 4 + q4;
                fv[nd][ks] = *(const short8*)(Vs + (d * 8 + (oct ^ (d & 7))) * 8);
            }
#pragma unroll
        for (int mt = 0; mt < 2; ++mt) {
#pragma unroll
            for (int nd = 0; nd < 4; ++nd) {
                oacc[mt][nd] = __builtin_amdgcn_mfma_f32_16x16x32_bf16(
                    fp[mt][0], fv[nd][0], oacc[mt][nd], 0, 0, 0);
                oacc[mt][nd] = __builtin_amdgcn_mfma_f32_16x16x32_bf16(
                    fp[mt][1], fv[nd][1], oacc[mt][nd], 0, 0, 0);
            }
            lacc[mt] = __builtin_amdgcn_mfma_f32_16x16x32_bf16(
                fp[mt][0], ones, lacc[mt], 0, 0, 0);
            lacc[mt] = __builtin_amdgcn_mfma_f32_16x16x32_bf16(
                fp[mt][1], ones, lacc[mt], 0, 0, 0);
        }

        __syncthreads();   // A: all waves done reading Vs
        if (it + 1 < SEQ / 64) {           // V(it+1) into Vs, in flight until B
            ASYNC16(vp0, Vs + sb0 * 8);
            ASYNC16(vp1, Vs + sb1 * 8);
            vp0 += 64; vp1 += 64;
        }
    }

    // ---- epilogue: lacc rows match oacc rows exactly; no shuffles ----
#pragma unroll
    for (int mt = 0; mt < 2; ++mt) {
        floatx4 rinv;
#pragma unroll
        for (int r = 0; r < 4; ++r) rinv[r] = 1.0f / lacc[mt][r];
#pragma unroll
        for (int nd = 0; nd < 4; ++nd)
#pragma unroll
            for (int r = 0; r < 4; ++r) {
                const int row = b * SEQ + q0 + wave * 32 + mt * 16 + q4 * 4 + r;
                const int col = hh * 64 + nd * 16 + l15;
                ab[(size_t)row * F_DIMC + col] = f2bf(oacc[mt][nd][r] * rinv[r]);
            }
    }
}

// ---------------------------------------------------------------------------
// Launcher. Workspace (u16 units, 52M u16 = 104 MB):
//   wbuf [0,12M) | h [12M,20M) | qb [20M,28M) | kb [28M,36M) | vtb [36M,44M)
//   ab [44M,52M) | ff overlays qb..vtb (32M) after attention consumed.
// ---------------------------------------------------------------------------
extern "C" void kernel_launch(void* const* d_in, const int* in_sizes, int n_in,
                              void* d_out, int out_size, void* d_ws, size_t ws_size,
                              hipStream_t stream) {
    const float* x     = (const float*)d_in[0];
    const float* ln1_w = (const float*)d_in[1];
    const float* ln1_b = (const float*)d_in[2];
    const float* wq_w  = (const float*)d_in[3];
    const float* wq_b  = (const float*)d_in[4];
    const float* wk_w  = (const float*)d_in[5];
    const float* wk_b  = (const float*)d_in[6];
    const float* wv_w  = (const float*)d_in[7];
    const float* wv_b  = (const float*)d_in[8];
    const float* fc_w  = (const float*)d_in[9];
    const float* fc_b  = (const float*)d_in[10];
    const float* ln2_w = (const float*)d_in[11];
    const float* ln2_b = (const float*)d_in[12];
    const float* fc1_w = (const float*)d_in[13];
    const float* fc1_b = (const float*)d_in[14];
    const float* fc2_w = (const float*)d_in[15];
    const float* fc2_b = (const float*)d_in[16];

    float* out = (float*)d_out;
    u16t*  ws  = (u16t*)d_ws;

    u16t* wbuf = ws;
    u16t* bwqkv = wbuf;                 // [3072][1024] fused
    u16t* bwfc = wbuf + 3 * MEG;
    u16t* bwf1 = wbuf + 4 * MEG;
    u16t* bwf2 = wbuf + 8 * MEG;
    u16t* h    = wbuf + 12 * MEG;
    u16t* qb   = h + 8 * MEG;
    u16t* kb   = qb + 8 * MEG;
    u16t* vtb  = kb + 8 * MEG;
    u16t* ab   = vtb + 8 * MEG;
    u16t* ff   = qb;                    // overlay: qb/kb/vtb dead by step 6

    const dim3 blk(256);
    const dim3 blk512(512);
    // 1D grids: (M/256)*(N/256); all divisible by 8 (XCD swizzle bijective)
    const int gQKV = 32 * (3072 / 256);     // 384
    const int gF   = 32 * (F_DIMC / 256);   // 128
    const int gH   = 32 * (HIDC / 256);     // 512

    // 0. weights -> bf16
    wconv_kernel<<<12 * MEG / 1024, blk, 0, stream>>>(wq_w, wk_w, wv_w, fc_w, fc1_w, fc2_w, wbuf);
    // 1. h = LN1(x)
    ln_kernel<<<ROWS, blk, 0, stream>>>(x, ln1_w, ln1_b, h);
    // 2. fused q (scaled), k, v^T
    gemm_qkv<<<gQKV, blk512, 0, stream>>>(h, bwqkv, wq_b, wk_b, wv_b, qb, kb, vtb);
    // 3. attention (MFMA flash v3)
    attn_mfma<<<dim3(SEQ / 128, BATCH * NH), blk, 0, stream>>>(qb, kb, vtb, ab);
    // 4. x1 = x + attn @ fc_w.T + fc_b  (fp32, into d_out)
    gemm_dp<false, true, false><<<gF, blk512, 0, stream>>>(ab, bwfc, fc_b, x, out, F_DIMC, F_DIMC);
    // 5. h = LN2(x1)
    ln_kernel<<<ROWS, blk, 0, stream>>>(out, ln2_w, ln2_b, h);
    // 6. ff = relu(h @ fc1_w.T + fc1_b)
    gemm_dp<true, false, true><<<gH, blk512, 0, stream>>>(h, bwf1, fc1_b, nullptr, ff, HIDC, F_DIMC);
    // 7. out = x1 + ff @ fc2_w.T + fc2_b
    gemm_dp<false, true, false><<<gF, blk512, 0, stream>>>(ff, bwf2, fc2_b, out, out, F_DIMC, HIDC);
}

// Round 5
// 553.525 us; speedup vs baseline: 1.0548x; 1.0548x over previous
//
#include <hip/hip_runtime.h>

// Problem constants
#define F_DIMC 1024
#define HIDC   4096
#define NH     16
#define SEQ    2048
#define BATCH  4
#define ROWS   (BATCH * SEQ)                    // 8192
#define MEG    (1u << 20)
#define QSCALE 0.18033688011112042f             // 0.125 * log2(e)

typedef unsigned short u16t;
typedef __attribute__((ext_vector_type(8))) short short8;   // 8 bf16 (4 VGPRs) — MFMA A/B frag
typedef __attribute__((ext_vector_type(4))) float floatx4;  // MFMA C/D frag
typedef __attribute__((address_space(1))) void gvoid_t;
typedef __attribute__((address_space(3))) void lvoid_t;
#define ASYNC16(g, l) __builtin_amdgcn_global_load_lds((gvoid_t*)(g), (lvoid_t*)(l), 16, 0, 0)

#if __has_builtin(__builtin_amdgcn_exp2f)
#define EXP2(x) __builtin_amdgcn_exp2f(x)       // raw v_exp_f32 (1 trans op)
#else
#define EXP2(x) exp2f(x)
#endif

__device__ __forceinline__ u16t f2bf(float f) {           // RNE float->bf16
    union { float f; unsigned u; } v; v.f = f;
    unsigned r = v.u + 0x7fffu + ((v.u >> 16) & 1u);
    return (u16t)(r >> 16);
}
__device__ __forceinline__ unsigned fasu(float f) {
    union { float f; unsigned u; } v; v.f = f; return v.u;
}

// ---------------------------------------------------------------------------
// LayerNorm: one 256-thread block per row of 1024 floats; bf16 output.
// ---------------------------------------------------------------------------
__global__ __launch_bounds__(256) void ln_kernel(const float* __restrict__ x,
                                                 const float* __restrict__ w,
                                                 const float* __restrict__ b,
                                                 u16t* __restrict__ out) {
    const int row = blockIdx.x;
    const int t = threadIdx.x;
    const float* xp = x + (size_t)row * F_DIMC;

    float4 v = *(const float4*)(xp + t * 4);
    float s  = v.x + v.y + v.z + v.w;
    float ss = v.x * v.x + v.y * v.y + v.z * v.z + v.w * v.w;
    for (int off = 32; off; off >>= 1) {
        s  += __shfl_down(s, off);
        ss += __shfl_down(ss, off);
    }
    __shared__ float red[8];
    const int wid = t >> 6, lid = t & 63;
    if (lid == 0) { red[wid] = s; red[4 + wid] = ss; }
    __syncthreads();
    if (t == 0) {
        float S  = red[0] + red[1] + red[2] + red[3];
        float SS = red[4] + red[5] + red[6] + red[7];
        float mu  = S * (1.0f / F_DIMC);
        float var = SS * (1.0f / F_DIMC) - mu * mu;
        red[0] = mu;
        red[1] = rsqrtf(var + 1e-6f);
    }
    __syncthreads();
    const float mu = red[0], rs = red[1];

    float4 wv = *(const float4*)(w + t * 4);
    float4 bv = *(const float4*)(b + t * 4);
    ushort4 o = make_ushort4(f2bf((v.x - mu) * rs * wv.x + bv.x),
                             f2bf((v.y - mu) * rs * wv.y + bv.y),
                             f2bf((v.z - mu) * rs * wv.z + bv.z),
                             f2bf((v.w - mu) * rs * wv.w + bv.w));
    *(ushort4*)(out + (size_t)row * F_DIMC + t * 4) = o;
}

// ---------------------------------------------------------------------------
// Weight conversion fp32 -> bf16, all 6 matrices in one launch.
// wbuf layout: wq[0,1M) wk[1M,2M) wv[2M,3M) fc[3M,4M) fc1[4M,8M) fc2[8M,12M)
// ---------------------------------------------------------------------------
__global__ __launch_bounds__(256) void wconv_kernel(const float* __restrict__ w0,
        const float* __restrict__ w1, const float* __restrict__ w2,
        const float* __restrict__ w3, const float* __restrict__ w4,
        const float* __restrict__ w5, u16t* __restrict__ dst) {
    const size_t e = ((size_t)blockIdx.x * 256 + threadIdx.x) * 4;
    const float* src; size_t off;
    if      (e < 1 * MEG) { src = w0; off = e; }
    else if (e < 2 * MEG) { src = w1; off = e - 1 * MEG; }
    else if (e < 3 * MEG) { src = w2; off = e - 2 * MEG; }
    else if (e < 4 * MEG) { src = w3; off = e - 3 * MEG; }
    else if (e < 8 * MEG) { src = w4; off = e - 4 * MEG; }
    else                  { src = w5; off = e - 8 * MEG; }
    float4 f = *(const float4*)(src + off);
    *(ushort4*)(dst + e) = make_ushort4(f2bf(f.x), f2bf(f.y), f2bf(f.z), f2bf(f.w));
}

// ---------------------------------------------------------------------------
// GEMM core v5: m97 occupancy regime + counted vmcnt + conflict-free swizzle.
// Tile 128x128, BK=32, 256 threads = 4 waves as 2(M) x 2(N); per-wave 64x64
// output = acc[4][4] of 16x16x32 bf16 frags.
// LDS: double-buffered As[2][128][32] + Ws[2][128][32] = 32 KB total ->
// with __launch_bounds__(256,3): 3 blocks/CU (12 waves/CU) — cross-block
// wave overlap (m114) absorbs barrier/vmcnt stalls; this is the PROVEN m97
// mechanism (912 TF), not intra-block pipelining (R2-R4 all regressed).
// Swizzle: rows have 4 16B-blocks; phys slot = logical ^ (row&3). Staging
// dest linear, SOURCE pre-swizzled (rule 21); frag read slot = fq ^ (fm&3).
// Whole-wave frag read covers a contiguous 1KB region -> conflict-free.
// Per tile: 8 ds_read_b128 -> lgkm(0)+bar (reads certified) -> stage t+2
// into just-freed buffer (4 loads) -> vmcnt(4) (t+1 certified, t+2 in
// flight — never a cold drain mid-loop) -> bar -> 16 MFMA (registers,
// overlaps next iteration's read issue).
// ---------------------------------------------------------------------------
#define DP_CORE(Aq, Wq, Kdim)                                                  \
    __shared__ u16t As[2][128 * 32] __attribute__((aligned(16)));              \
    __shared__ u16t Ws[2][128 * 32] __attribute__((aligned(16)));              \
    const int t = threadIdx.x;                                                 \
    const int lane = t & 63;                                                   \
    const int wave = t >> 6;                                                   \
    const int wm = wave >> 1, wn = wave & 1;                                   \
    const int fm = lane & 15, fq = lane >> 4;                                  \
    /* XCD-aware bijective swizzle; m-index fastest so consecutive same-XCD    \
       blocks share the B-panel (L2-resident per XCD) */                       \
    const int nwg = gridDim.x;                                                 \
    const int swzb = (blockIdx.x & 7) * (nwg >> 3) + (blockIdx.x >> 3);        \
    const int m0 = (swzb & 63) * 128;          /* 64 m-blocks (M=8192) */      \
    const int n0 = (swzb >> 6) * 128;                                          \
    /* staging: thread covers 16B-blocks beta0, beta1 of the 8KB tile;         \
       source k-block j = (beta&3)^(row&3) — involution the reader undoes */   \
    const int beta0 = t, beta1 = t + 256;                                      \
    const int r0 = beta0 >> 2, j0 = (beta0 & 3) ^ (r0 & 3);                    \
    const int r1 = beta1 >> 2, j1 = (beta1 & 3) ^ (r1 & 3);                    \
    const u16t* ag0 = (Aq) + (size_t)(m0 + r0) * (Kdim) + j0 * 8;              \
    const u16t* ag1 = (Aq) + (size_t)(m0 + r1) * (Kdim) + j1 * 8;              \
    const u16t* wg0 = (Wq) + (size_t)(n0 + r0) * (Kdim) + j0 * 8;              \
    const u16t* wg1 = (Wq) + (size_t)(n0 + r1) * (Kdim) + j1 * 8;              \
    const int l0 = beta0 * 8, l1 = beta1 * 8;                                  \
    /* frag read bases: row = w*64 + mi*16 + fm => row&3 == fm&3 (mi-inv) */   \
    const int aoff = (wm * 64 + fm) * 32 + ((fq ^ (fm & 3)) * 8);              \
    const int boff = (wn * 64 + fm) * 32 + ((fq ^ (fm & 3)) * 8);              \
    const int NT = (Kdim) / 32;                                                \
    /* prologue: stage tiles 0,1 (8 loads); vmcnt(4) => tile0 landed */        \
    ASYNC16(ag0, &As[0][l0]); ASYNC16(ag1, &As[0][l1]);                        \
    ASYNC16(wg0, &Ws[0][l0]); ASYNC16(wg1, &Ws[0][l1]);                        \
    ASYNC16(ag0 + 32, &As[1][l0]); ASYNC16(ag1 + 32, &As[1][l1]);              \
    ASYNC16(wg0 + 32, &Ws[1][l0]); ASYNC16(wg1 + 32, &Ws[1][l1]);              \
    ag0 += 64; ag1 += 64; wg0 += 64; wg1 += 64;                                \
    asm volatile("s_waitcnt vmcnt(4)" ::: "memory");                           \
    __builtin_amdgcn_s_barrier();                                              \
    floatx4 acc[4][4] = {};                                                    \
    for (int tt = 0; tt < NT; ++tt) {                                          \
        const u16t* Ab = &As[tt & 1][0];                                       \
        const u16t* Wb = &Ws[tt & 1][0];                                       \
        short8 fa[4], fb[4];                                                   \
        _Pragma("unroll")                                                      \
        for (int i = 0; i < 4; ++i) {                                          \
            fa[i] = *(const short8*)(Ab + aoff + i * 512);                     \
            fb[i] = *(const short8*)(Wb + boff + i * 512);                     \
        }                                                                      \
        asm volatile("s_waitcnt lgkmcnt(0)" ::: "memory"); /* my reads done */ \
        __builtin_amdgcn_s_barrier();          /* ALL waves' reads done */     \
        if (tt + 2 < NT) {                                                     \
            u16t* la = &As[tt & 1][0]; u16t* lw = &Ws[tt & 1][0];              \
            ASYNC16(ag0, la + l0); ASYNC16(ag1, la + l1);                      \
            ASYNC16(wg0, lw + l0); ASYNC16(wg1, lw + l1);                      \
            ag0 += 32; ag1 += 32; wg0 += 32; wg1 += 32;                        \
            asm volatile("s_waitcnt vmcnt(4)" ::: "memory"); /* t+1 landed */  \
        } else {                                                               \
            asm volatile("s_waitcnt vmcnt(0)" ::: "memory");                   \
        }                                                                      \
        __builtin_amdgcn_s_barrier();          /* t+1 resident for all */      \
        __builtin_amdgcn_s_setprio(1);                                         \
        _Pragma("unroll")                                                      \
        for (int mi = 0; mi < 4; ++mi)                                         \
            _Pragma("unroll")                                                  \
            for (int ni = 0; ni < 4; ++ni)                                     \
                acc[mi][ni] = __builtin_amdgcn_mfma_f32_16x16x32_bf16(         \
                    fa[mi], fb[ni], acc[mi][ni], 0, 0, 0);                     \
        __builtin_amdgcn_s_setprio(0);                                         \
    }

// ---------------------------------------------------------------------------
// Generic bf16 MFMA GEMM: C = A @ W^T + bias (+ReLU)(+res)
// 1D grid = (M/128)*(N/128), 256 threads, 3 blocks/CU.
// ---------------------------------------------------------------------------
template <bool RELU, bool RES, bool BF16OUT>
__global__ __launch_bounds__(256, 3) void gemm_dp(const u16t* __restrict__ A,
                                                  const u16t* __restrict__ W,
                                                  const float* __restrict__ bias,
                                                  const float* res, void* Cout,
                                                  int N, int K) {
    DP_CORE(A, W, K)
    // Epilogue. C/D layout: col=lane&15, row=(lane>>4)*4+reg  [m89/m91].
    float bl[4];
#pragma unroll
    for (int ni = 0; ni < 4; ++ni) bl[ni] = bias[n0 + wn * 64 + ni * 16 + fm];
#pragma unroll
    for (int mi = 0; mi < 4; ++mi) {
#pragma unroll
        for (int ni = 0; ni < 4; ++ni) {
            const int col = n0 + wn * 64 + ni * 16 + fm;
#pragma unroll
            for (int r = 0; r < 4; ++r) {
                const int row = m0 + wm * 64 + mi * 16 + fq * 4 + r;
                const size_t off = (size_t)row * N + col;
                float c = acc[mi][ni][r] + bl[ni];
                if (RELU) c = fmaxf(c, 0.0f);
                if (RES)  c += res[off];
                if (BF16OUT) ((u16t*)Cout)[off] = f2bf(c);
                else         ((float*)Cout)[off] = c;
            }
        }
    }
}

// ---------------------------------------------------------------------------
// Fused QKV GEMM: A = h [8192][1024], W = W_qkv [3072][1024].
// n0 multiple of 128 never straddles the q/k/v 1024-boundaries. Routes:
// q (scaled) -> qb, k -> kb, v -> vtb TRANSPOSED (vtb[d][token]).
// 1D grid = 64*(3072/128) = 1536, 256 threads.
// ---------------------------------------------------------------------------
__global__ __launch_bounds__(256, 3) void gemm_qkv(const u16t* __restrict__ A,
        const u16t* __restrict__ W,
        const float* __restrict__ wq_b, const float* __restrict__ wk_b,
        const float* __restrict__ wv_b,
        u16t* __restrict__ qb, u16t* __restrict__ kb, u16t* __restrict__ vtb) {
    DP_CORE(A, W, F_DIMC)
    const int which = n0 >> 10;                 // 0=q 1=k 2=v
    const int nb = n0 & 1023;
    const float* bias = which == 0 ? wq_b : which == 1 ? wk_b : wv_b;
    float bl[4];
#pragma unroll
    for (int ni = 0; ni < 4; ++ni) bl[ni] = bias[nb + wn * 64 + ni * 16 + fm];

    if (which == 2) {
        // v: transposed store, 4 consecutive tokens packed per ushort4
#pragma unroll
        for (int mi = 0; mi < 4; ++mi)
#pragma unroll
            for (int ni = 0; ni < 4; ++ni) {
                const int col = nb + wn * 64 + ni * 16 + fm;       // d index
                const int row0 = m0 + wm * 64 + mi * 16 + fq * 4;  // token
                ushort4 pk = make_ushort4(f2bf(acc[mi][ni][0] + bl[ni]),
                                          f2bf(acc[mi][ni][1] + bl[ni]),
                                          f2bf(acc[mi][ni][2] + bl[ni]),
                                          f2bf(acc[mi][ni][3] + bl[ni]));
                *(ushort4*)(vtb + (size_t)col * ROWS + row0) = pk;
            }
    } else {
        u16t* dst = (which == 0) ? qb : kb;
        const float sc2 = (which == 0) ? QSCALE : 1.0f;
#pragma unroll
        for (int mi = 0; mi < 4; ++mi)
#pragma unroll
            for (int ni = 0; ni < 4; ++ni) {
                const int col = nb + wn * 64 + ni * 16 + fm;
#pragma unroll
                for (int r = 0; r < 4; ++r) {
                    const int row = m0 + wm * 64 + mi * 16 + fq * 4 + r;
                    dst[(size_t)row * F_DIMC + col] = f2bf((acc[mi][ni][r] + bl[ni]) * sc2);
                }
            }
    }
}

// ---------------------------------------------------------------------------
// MFMA flash attention, v3 (unchanged this round).
// ---------------------------------------------------------------------------
__global__ __launch_bounds__(256, 4) void attn_mfma(const u16t* __restrict__ qb,
        const u16t* __restrict__ kbuf, const u16t* __restrict__ vtb,
        u16t* __restrict__ ab) {
    __shared__ u16t Kt[2][64 * 64] __attribute__((aligned(16)));   // 16 KB
    __shared__ u16t Vs[64 * 64] __attribute__((aligned(16)));      // 8 KB
    __shared__ u16t QP[128 * 64] __attribute__((aligned(16)));     // 16 KB

    const int t = threadIdx.x;
    const int lane = t & 63;
    const int wave = t >> 6;
    const int l15 = lane & 15, q4 = lane >> 4;
    const int q0 = blockIdx.x * 128;
    const int bh = blockIdx.y;
    const int b = bh >> 4, hh = bh & 15;

    // ---- stage Q (cooperative): 1024 16B-blocks, swizzled ----
#pragma unroll
    for (int c = 0; c < 4; ++c) {
        const int beta = c * 256 + t;
        const int r = beta >> 3, o = (beta & 7) ^ (r & 7);
        ASYNC16(qb + (size_t)(b * SEQ + q0 + r) * F_DIMC + hh * 64 + o * 8,
                QP + beta * 8);
    }
    const u16t* kg = kbuf + (size_t)(b * SEQ) * F_DIMC + hh * 64;
    const u16t* vg = vtb + (size_t)(hh * 64) * ROWS + b * SEQ;

    // per-thread staging coords (loop-invariant)
    const int sb0 = t, sb1 = t + 256;
    const int sr0 = sb0 >> 3, so0 = (sb0 & 7) ^ (sr0 & 7);
    const int sr1 = sb1 >> 3, so1 = (sb1 & 7) ^ (sr1 & 7);
    const u16t* kp0 = kg + (size_t)sr0 * F_DIMC + so0 * 8;
    const u16t* kp1 = kg + (size_t)sr1 * F_DIMC + so1 * 8;
    const u16t* vp0 = vg + (size_t)sr0 * ROWS + so0 * 8;
    const u16t* vp1 = vg + (size_t)sr1 * ROWS + so1 * 8;

    // ---- pre-stage K0 -> Kt[0], V0 -> Vs ----
    ASYNC16(kp0, Kt[0] + sb0 * 8);
    ASYNC16(kp1, Kt[0] + sb1 * 8);
    ASYNC16(vp0, Vs + sb0 * 8);
    ASYNC16(vp1, Vs + sb1 * 8);
    kp0 += 64 * F_DIMC; kp1 += 64 * F_DIMC; vp0 += 64; vp1 += 64;
    __syncthreads();                       // Q + tile0 resident

    // ---- Q B-frags (this wave's 32 rows) ----
    short8 fqr[2][2];
#pragma unroll
    for (int mt = 0; mt < 2; ++mt)
#pragma unroll
        for (int ks = 0; ks < 2; ++ks) {
            const int m = wave * 32 + mt * 16 + l15;
            const int oct = ks * 4 + q4;
            fqr[mt][ks] = *(const short8*)(QP + (m * 8 + (oct ^ (m & 7))) * 8);
        }
    // From here QP rows [wave*32, wave*32+32) are private to this wave (P).

    short8 ones;                           // bf16 1.0 broadcast (B operand)
#pragma unroll
    for (int i = 0; i < 8; ++i) ones[i] = (short)0x3F80;

    floatx4 oacc[2][4] = {};
    floatx4 lacc[2] = {};

    for (int it = 0; it < SEQ / 64; ++it) {
        // prefetch K(it+1) into the other K buffer
        if (it + 1 < SEQ / 64) {
            u16t* kd = Kt[(it + 1) & 1];
            ASYNC16(kp0, kd + sb0 * 8);
            ASYNC16(kp1, kd + sb1 * 8);
            kp0 += 64 * F_DIMC; kp1 += 64 * F_DIMC;
        }
        const u16t* kcur = Kt[it & 1];

        // ---- S^T = K @ Q^T : C rows = keys, cols = queries ----
        short8 fk[4][2];
#pragma unroll
        for (int nt = 0; nt < 4; ++nt)
#pragma unroll
            for (int ks = 0; ks < 2; ++ks) {
                const int kr = nt * 16 + l15;
                const int oct = ks * 4 + q4;
                fk[nt][ks] = *(const short8*)(kcur + (kr * 8 + (oct ^ (kr & 7))) * 8);
            }
        floatx4 st[2][4] = {};
#pragma unroll
        for (int mt = 0; mt < 2; ++mt)
#pragma unroll
            for (int nt = 0; nt < 4; ++nt) {
                st[mt][nt] = __builtin_amdgcn_mfma_f32_16x16x32_bf16(
                    fk[nt][0], fqr[mt][0], st[mt][nt], 0, 0, 0);
                st[mt][nt] = __builtin_amdgcn_mfma_f32_16x16x32_bf16(
                    fk[nt][1], fqr[mt][1], st[mt][nt], 0, 0, 0);
            }

        // ---- P = exp2(S^T), truncate-pack via v_perm, b64 writes (own rows)
#pragma unroll
        for (int mt = 0; mt < 2; ++mt)
#pragma unroll
            for (int nt = 0; nt < 4; ++nt) {
                const float p0 = EXP2(st[mt][nt][0]);
                const float p1 = EXP2(st[mt][nt][1]);
                const float p2 = EXP2(st[mt][nt][2]);
                const float p3 = EXP2(st[mt][nt][3]);
                const unsigned lo = __builtin_amdgcn_perm(fasu(p1), fasu(p0), 0x07060302u);
                const unsigned hi = __builtin_amdgcn_perm(fasu(p3), fasu(p2), 0x07060302u);
                const int m = wave * 32 + mt * 16 + l15;
                const int logb = nt * 2 + (q4 >> 1);       // 16B-block of k0
                *(uint2*)(QP + (m * 8 + (logb ^ (m & 7))) * 8 + (q4 & 1) * 4) =
                    make_uint2(lo, hi);
            }

        __syncthreads();   // B: drains V(it) (issued last iter) + K(it+1)

        // ---- O += P @ V ;  l += P @ 1 ----
        short8 fp[2][2], fv[4][2];
#pragma unroll
        for (int mt = 0; mt < 2; ++mt)
#pragma unroll
            for (int ks = 0; ks < 2; ++ks) {
                const int m = wave * 32 + mt * 16 + l15;
                const int oct = ks * 4 + q4;
                fp[mt][ks] = *(const short8*)(QP + (m * 8 + (oct ^ (m & 7))) * 8);
            }
#pragma unroll
        for (int nd = 0; nd < 4; ++nd)
#pragma unroll
            for (int ks = 0; ks < 2; ++ks) {
                const int d = nd * 16 + l15;
                const int oct = ks * 4 + q4;
                fv[nd][ks] = *(const short8*)(Vs + (d * 8 + (oct ^ (d & 7))) * 8);
            }
#pragma unroll
        for (int mt = 0; mt < 2; ++mt) {
#pragma unroll
            for (int nd = 0; nd < 4; ++nd) {
                oacc[mt][nd] = __builtin_amdgcn_mfma_f32_16x16x32_bf16(
                    fp[mt][0], fv[nd][0], oacc[mt][nd], 0, 0, 0);
                oacc[mt][nd] = __builtin_amdgcn_mfma_f32_16x16x32_bf16(
                    fp[mt][1], fv[nd][1], oacc[mt][nd], 0, 0, 0);
            }
            lacc[mt] = __builtin_amdgcn_mfma_f32_16x16x32_bf16(
                fp[mt][0], ones, lacc[mt], 0, 0, 0);
            lacc[mt] = __builtin_amdgcn_mfma_f32_16x16x32_bf16(
                fp[mt][1], ones, lacc[mt], 0, 0, 0);
        }

        __syncthreads();   // A: all waves done reading Vs
        if (it + 1 < SEQ / 64) {           // V(it+1) into Vs, in flight until B
            ASYNC16(vp0, Vs + sb0 * 8);
            ASYNC16(vp1, Vs + sb1 * 8);
            vp0 += 64; vp1 += 64;
        }
    }

    // ---- epilogue: lacc rows match oacc rows exactly; no shuffles ----
#pragma unroll
    for (int mt = 0; mt < 2; ++mt) {
        floatx4 rinv;
#pragma unroll
        for (int r = 0; r < 4; ++r) rinv[r] = 1.0f / lacc[mt][r];
#pragma unroll
        for (int nd = 0; nd < 4; ++nd)
#pragma unroll
            for (int r = 0; r < 4; ++r) {
                const int row = b * SEQ + q0 + wave * 32 + mt * 16 + q4 * 4 + r;
                const int col = hh * 64 + nd * 16 + l15;
                ab[(size_t)row * F_DIMC + col] = f2bf(oacc[mt][nd][r] * rinv[r]);
            }
    }
}

// ---------------------------------------------------------------------------
// Launcher. Workspace (u16 units, 52M u16 = 104 MB):
//   wbuf [0,12M) | h [12M,20M) | qb [20M,28M) | kb [28M,36M) | vtb [36M,44M)
//   ab [44M,52M) | ff overlays qb..vtb (32M) after attention consumed.
// ---------------------------------------------------------------------------
extern "C" void kernel_launch(void* const* d_in, const int* in_sizes, int n_in,
                              void* d_out, int out_size, void* d_ws, size_t ws_size,
                              hipStream_t stream) {
    const float* x     = (const float*)d_in[0];
    const float* ln1_w = (const float*)d_in[1];
    const float* ln1_b = (const float*)d_in[2];
    const float* wq_w  = (const float*)d_in[3];
    const float* wq_b  = (const float*)d_in[4];
    const float* wk_w  = (const float*)d_in[5];
    const float* wk_b  = (const float*)d_in[6];
    const float* wv_w  = (const float*)d_in[7];
    const float* wv_b  = (const float*)d_in[8];
    const float* fc_w  = (const float*)d_in[9];
    const float* fc_b  = (const float*)d_in[10];
    const float* ln2_w = (const float*)d_in[11];
    const float* ln2_b = (const float*)d_in[12];
    const float* fc1_w = (const float*)d_in[13];
    const float* fc1_b = (const float*)d_in[14];
    const float* fc2_w = (const float*)d_in[15];
    const float* fc2_b = (const float*)d_in[16];

    float* out = (float*)d_out;
    u16t*  ws  = (u16t*)d_ws;

    u16t* wbuf = ws;
    u16t* bwqkv = wbuf;                 // [3072][1024] fused
    u16t* bwfc = wbuf + 3 * MEG;
    u16t* bwf1 = wbuf + 4 * MEG;
    u16t* bwf2 = wbuf + 8 * MEG;
    u16t* h    = wbuf + 12 * MEG;
    u16t* qb   = h + 8 * MEG;
    u16t* kb   = qb + 8 * MEG;
    u16t* vtb  = kb + 8 * MEG;
    u16t* ab   = vtb + 8 * MEG;
    u16t* ff   = qb;                    // overlay: qb/kb/vtb dead by step 6

    const dim3 blk(256);
    // 1D grids: (M/128)*(N/128); all divisible by 8 (XCD swizzle bijective)
    const int gQKV = 64 * (3072 / 128);     // 1536
    const int gF   = 64 * (F_DIMC / 128);   // 512
    const int gH   = 64 * (HIDC / 128);     // 2048

    // 0. weights -> bf16
    wconv_kernel<<<12 * MEG / 1024, blk, 0, stream>>>(wq_w, wk_w, wv_w, fc_w, fc1_w, fc2_w, wbuf);
    // 1. h = LN1(x)
    ln_kernel<<<ROWS, blk, 0, stream>>>(x, ln1_w, ln1_b, h);
    // 2. fused q (scaled), k, v^T
    gemm_qkv<<<gQKV, blk, 0, stream>>>(h, bwqkv, wq_b, wk_b, wv_b, qb, kb, vtb);
    // 3. attention (MFMA flash v3)
    attn_mfma<<<dim3(SEQ / 128, BATCH * NH), blk, 0, stream>>>(qb, kb, vtb, ab);
    // 4. x1 = x + attn @ fc_w.T + fc_b  (fp32, into d_out)
    gemm_dp<false, true, false><<<gF, blk, 0, stream>>>(ab, bwfc, fc_b, x, out, F_DIMC, F_DIMC);
    // 5. h = LN2(x1)
    ln_kernel<<<ROWS, blk, 0, stream>>>(out, ln2_w, ln2_b, h);
    // 6. ff = relu(h @ fc1_w.T + fc1_b)
    gemm_dp<true, false, true><<<gH, blk, 0, stream>>>(h, bwf1, fc1_b, nullptr, ff, HIDC, F_DIMC);
    // 7. out = x1 + ff @ fc2_w.T + fc2_b
    gemm_dp<false, true, false><<<gF, blk, 0, stream>>>(ff, bwf2, fc2_b, out, out, F_DIMC, HIDC);
}

// Round 6
// 513.973 us; speedup vs baseline: 1.1359x; 1.0770x over previous
//
#include <hip/hip_runtime.h>

// Problem constants
#define F_DIMC 1024
#define HIDC   4096
#define NH     16
#define SEQ    2048
#define BATCH  4
#define ROWS   (BATCH * SEQ)                    // 8192
#define MEG    (1u << 20)
#define QSCALE 0.18033688011112042f             // 0.125 * log2(e)

typedef unsigned short u16t;
typedef __attribute__((ext_vector_type(8))) short short8;   // 8 bf16 (4 VGPRs) — MFMA A/B frag
typedef __attribute__((ext_vector_type(4))) float floatx4;  // MFMA C/D frag
typedef __attribute__((address_space(1))) void gvoid_t;
typedef __attribute__((address_space(3))) void lvoid_t;
#define ASYNC16(g, l) __builtin_amdgcn_global_load_lds((gvoid_t*)(g), (lvoid_t*)(l), 16, 0, 0)

#if __has_builtin(__builtin_amdgcn_exp2f)
#define EXP2(x) __builtin_amdgcn_exp2f(x)       // raw v_exp_f32 (1 trans op)
#else
#define EXP2(x) exp2f(x)
#endif

__device__ __forceinline__ u16t f2bf(float f) {           // RNE float->bf16
    union { float f; unsigned u; } v; v.f = f;
    unsigned r = v.u + 0x7fffu + ((v.u >> 16) & 1u);
    return (u16t)(r >> 16);
}
__device__ __forceinline__ unsigned fasu(float f) {
    union { float f; unsigned u; } v; v.f = f; return v.u;
}

// ---------------------------------------------------------------------------
// LayerNorm: one 256-thread block per row of 1024 floats; bf16 output.
// ---------------------------------------------------------------------------
__global__ __launch_bounds__(256) void ln_kernel(const float* __restrict__ x,
                                                 const float* __restrict__ w,
                                                 const float* __restrict__ b,
                                                 u16t* __restrict__ out) {
    const int row = blockIdx.x;
    const int t = threadIdx.x;
    const float* xp = x + (size_t)row * F_DIMC;

    float4 v = *(const float4*)(xp + t * 4);
    float s  = v.x + v.y + v.z + v.w;
    float ss = v.x * v.x + v.y * v.y + v.z * v.z + v.w * v.w;
    for (int off = 32; off; off >>= 1) {
        s  += __shfl_down(s, off);
        ss += __shfl_down(ss, off);
    }
    __shared__ float red[8];
    const int wid = t >> 6, lid = t & 63;
    if (lid == 0) { red[wid] = s; red[4 + wid] = ss; }
    __syncthreads();
    if (t == 0) {
        float S  = red[0] + red[1] + red[2] + red[3];
        float SS = red[4] + red[5] + red[6] + red[7];
        float mu  = S * (1.0f / F_DIMC);
        float var = SS * (1.0f / F_DIMC) - mu * mu;
        red[0] = mu;
        red[1] = rsqrtf(var + 1e-6f);
    }
    __syncthreads();
    const float mu = red[0], rs = red[1];

    float4 wv = *(const float4*)(w + t * 4);
    float4 bv = *(const float4*)(b + t * 4);
    ushort4 o = make_ushort4(f2bf((v.x - mu) * rs * wv.x + bv.x),
                             f2bf((v.y - mu) * rs * wv.y + bv.y),
                             f2bf((v.z - mu) * rs * wv.z + bv.z),
                             f2bf((v.w - mu) * rs * wv.w + bv.w));
    *(ushort4*)(out + (size_t)row * F_DIMC + t * 4) = o;
}

// ---------------------------------------------------------------------------
// Weight conversion fp32 -> bf16, all 6 matrices in one launch.
// wbuf layout: wq[0,1M) wk[1M,2M) wv[2M,3M) fc[3M,4M) fc1[4M,8M) fc2[8M,12M)
// ---------------------------------------------------------------------------
__global__ __launch_bounds__(256) void wconv_kernel(const float* __restrict__ w0,
        const float* __restrict__ w1, const float* __restrict__ w2,
        const float* __restrict__ w3, const float* __restrict__ w4,
        const float* __restrict__ w5, u16t* __restrict__ dst) {
    const size_t e = ((size_t)blockIdx.x * 256 + threadIdx.x) * 4;
    const float* src; size_t off;
    if      (e < 1 * MEG) { src = w0; off = e; }
    else if (e < 2 * MEG) { src = w1; off = e - 1 * MEG; }
    else if (e < 3 * MEG) { src = w2; off = e - 2 * MEG; }
    else if (e < 4 * MEG) { src = w3; off = e - 3 * MEG; }
    else if (e < 8 * MEG) { src = w4; off = e - 4 * MEG; }
    else                  { src = w5; off = e - 8 * MEG; }
    float4 f = *(const float4*)(src + off);
    *(ushort4*)(dst + e) = make_ushort4(f2bf(f.x), f2bf(f.y), f2bf(f.z), f2bf(f.w));
}

// ---------------------------------------------------------------------------
// Deep-pipeline GEMM core (VERIFIED BEST — R1, 103 µs/27% MfmaUtil/0 confl).
// Tile 256(M) x 128(N), BK=64, 512 threads = 8 waves as 4(M) x 2(N);
// per-wave 64x64 output = acc[4][4] of 16x16x32 bf16 MFMA frags.
// LDS: double-buffered A[2][256][64] (64 KB) + W[2][128][64] (32 KB) = 96 KB.
// LDS layout: row-major, 16B blocks XOR-swizzled: physical = logical ^ (row&7).
// global_load_lds writes linearly; the global SOURCE address is pre-swizzled
// (rule 21: linear dest + inverse-swizzled source + swizzled read).
// Pipeline: stage tile t+2 into buf[t&1] AFTER all tile-t reads done
// (lgkmcnt(0)+barrier); vmcnt(6) certifies tile t+1 while t+2 stays in flight.
// Steady state never drains vmcnt to 0 (T4). DO NOT TOUCH — R2-R5 departures
// (3-ring, 8-phase x2, 128^2@BK32) all measured worse (109/138/148/113 µs).
// ---------------------------------------------------------------------------
#define DP_PROLOGUE_AND_LOOP(Aq, Wq, Kdim, NBX)                                \
    __shared__ u16t As[2][256 * 64] __attribute__((aligned(16)));              \
    __shared__ u16t Ws[2][128 * 64] __attribute__((aligned(16)));              \
    const int t = threadIdx.x;                                                 \
    const int lane = t & 63;                                                   \
    const int wave = t >> 6;                                                   \
    const int wm = wave >> 1, wn = wave & 1;                                   \
    const int fm = lane & 15, fq = lane >> 4;                                  \
    const int l7 = lane & 7;                                                   \
    /* XCD-aware bijective swizzle of flat block id (grid always %8==0) */     \
    const int nwg = gridDim.x;                                                 \
    const int swzb = (blockIdx.x & 7) * (nwg >> 3) + (blockIdx.x >> 3);        \
    const int m0 = (swzb / (NBX)) * 256, n0 = (swzb % (NBX)) * 128;            \
    /* per-thread staging coords: dest block beta (linear), source k-block     \
       j = (beta&7) ^ (row&7)  (the involution the reader undoes) */           \
    const u16t* ag[4]; const u16t* wg2[2];                                     \
    int alo[4]; int wlo[2];                                                    \
    _Pragma("unroll")                                                          \
    for (int i = 0; i < 4; ++i) {                                              \
        const int beta = i * 512 + t;                                          \
        const int r = beta >> 3, j = (beta & 7) ^ (r & 7);                     \
        ag[i] = (Aq) + (size_t)(m0 + r) * (Kdim) + j * 8;                      \
        alo[i] = beta * 8;                                                     \
    }                                                                          \
    _Pragma("unroll")                                                          \
    for (int i = 0; i < 2; ++i) {                                              \
        const int beta = i * 512 + t;                                          \
        const int r = beta >> 3, j = (beta & 7) ^ (r & 7);                     \
        wg2[i] = (Wq) + (size_t)(n0 + r) * (Kdim) + j * 8;                     \
        wlo[i] = beta * 8;                                                     \
    }                                                                          \
    /* frag read bases (u16 offsets within one buffer), per k-slice ks */      \
    int abase[2], bbase[2];                                                    \
    _Pragma("unroll")                                                          \
    for (int ks = 0; ks < 2; ++ks) {                                           \
        const int sw = (ks * 4 + fq) ^ l7;                                     \
        abase[ks] = (wm * 64 + fm) * 64 + sw * 8;                              \
        bbase[ks] = (wn * 64 + fm) * 64 + sw * 8;                              \
    }                                                                          \
    const int NT = (Kdim) / 64;                                                \
    /* prologue: stage tiles 0 and 1 (12 loads in flight) */                   \
    _Pragma("unroll")                                                          \
    for (int i = 0; i < 4; ++i) ASYNC16(ag[i], &As[0][alo[i]]);                \
    _Pragma("unroll")                                                          \
    for (int i = 0; i < 2; ++i) ASYNC16(wg2[i], &Ws[0][wlo[i]]);               \
    _Pragma("unroll")                                                          \
    for (int i = 0; i < 4; ++i) ASYNC16(ag[i] + 64, &As[1][alo[i]]);           \
    _Pragma("unroll")                                                          \
    for (int i = 0; i < 2; ++i) ASYNC16(wg2[i] + 64, &Ws[1][wlo[i]]);          \
    _Pragma("unroll")                                                          \
    for (int i = 0; i < 4; ++i) ag[i] += 128;                                  \
    _Pragma("unroll")                                                          \
    for (int i = 0; i < 2; ++i) wg2[i] += 128;                                 \
    asm volatile("s_waitcnt vmcnt(6)" ::: "memory");   /* tile0 landed */      \
    __builtin_amdgcn_s_barrier();                                              \
    __builtin_amdgcn_sched_barrier(0);                                         \
    floatx4 acc[4][4] = {};                                                    \
    for (int tt = 0; tt < NT; ++tt) {                                          \
        const u16t* Ab = As[tt & 1];                                           \
        const u16t* Wb = Ws[tt & 1];                                           \
        /* ---- slice 0: read frags, MFMA ---- */                              \
        short8 fa[4], fb[4];                                                   \
        _Pragma("unroll")                                                      \
        for (int mi = 0; mi < 4; ++mi)                                         \
            fa[mi] = *(const short8*)(Ab + abase[0] + mi * 1024);              \
        _Pragma("unroll")                                                      \
        for (int ni = 0; ni < 4; ++ni)                                         \
            fb[ni] = *(const short8*)(Wb + bbase[0] + ni * 1024);              \
        __builtin_amdgcn_s_setprio(1);                                         \
        _Pragma("unroll")                                                      \
        for (int mi = 0; mi < 4; ++mi)                                         \
            _Pragma("unroll")                                                  \
            for (int ni = 0; ni < 4; ++ni)                                     \
                acc[mi][ni] = __builtin_amdgcn_mfma_f32_16x16x32_bf16(         \
                    fa[mi], fb[ni], acc[mi][ni], 0, 0, 0);                     \
        __builtin_amdgcn_s_setprio(0);                                         \
        /* ---- slice 1 reads (overlap slice-0 MFMA drain) ---- */             \
        short8 fa1[4], fb1[4];                                                 \
        _Pragma("unroll")                                                      \
        for (int mi = 0; mi < 4; ++mi)                                         \
            fa1[mi] = *(const short8*)(Ab + abase[1] + mi * 1024);             \
        _Pragma("unroll")                                                      \
        for (int ni = 0; ni < 4; ++ni)                                         \
            fb1[ni] = *(const short8*)(Wb + bbase[1] + ni * 1024);             \
        asm volatile("s_waitcnt lgkmcnt(0)" ::: "memory"); /* all my reads done */ \
        __builtin_amdgcn_s_barrier();       /* => ALL waves done reading buf */ \
        __builtin_amdgcn_sched_barrier(0);                                     \
        if (tt + 2 < NT) {                                                     \
            const int pb = tt & 1;          /* overwrite the buffer just read */ \
            _Pragma("unroll")                                                  \
            for (int i = 0; i < 4; ++i) {                                      \
                ASYNC16(ag[i], &As[pb][alo[i]]); ag[i] += 64;                  \
            }                                                                  \
            _Pragma("unroll")                                                  \
            for (int i = 0; i < 2; ++i) {                                      \
                ASYNC16(wg2[i], &Ws[pb][wlo[i]]); wg2[i] += 64;                \
            }                                                                  \
            /* wait tile t+1 landed; t+2's 6 loads stay in flight (T4) */      \
            asm volatile("s_waitcnt vmcnt(6)" ::: "memory");                   \
        } else {                                                               \
            asm volatile("s_waitcnt vmcnt(0)" ::: "memory");                   \
        }                                                                      \
        __builtin_amdgcn_s_barrier();                                          \
        __builtin_amdgcn_sched_barrier(0);                                     \
        /* ---- slice 1 MFMA (overlaps next tile's slice-0 reads) ---- */      \
        __builtin_amdgcn_s_setprio(1);                                         \
        _Pragma("unroll")                                                      \
        for (int mi = 0; mi < 4; ++mi)                                         \
            _Pragma("unroll")                                                  \
            for (int ni = 0; ni < 4; ++ni)                                     \
                acc[mi][ni] = __builtin_amdgcn_mfma_f32_16x16x32_bf16(         \
                    fa1[mi], fb1[ni], acc[mi][ni], 0, 0, 0);                   \
        __builtin_amdgcn_s_setprio(0);                                         \
    }

// ---------------------------------------------------------------------------
// Generic bf16 MFMA GEMM: C = A @ W^T + bias (+ReLU)(+res)
// 1D grid = (M/256)*(N/128), 512 threads.
// ---------------------------------------------------------------------------
template <bool RELU, bool RES, bool BF16OUT>
__global__ __launch_bounds__(512, 2) void gemm_dp(const u16t* __restrict__ A,
                                                  const u16t* __restrict__ W,
                                                  const float* __restrict__ bias,
                                                  const float* res, void* Cout,
                                                  int N, int K) {
    DP_PROLOGUE_AND_LOOP(A, W, K, N / 128)
    // Epilogue. C/D layout: col=lane&15, row=(lane>>4)*4+reg  [m89/m91].
    float bl[4];
#pragma unroll
    for (int ni = 0; ni < 4; ++ni) bl[ni] = bias[n0 + wn * 64 + ni * 16 + fm];
#pragma unroll
    for (int mi = 0; mi < 4; ++mi) {
#pragma unroll
        for (int ni = 0; ni < 4; ++ni) {
            const int col = n0 + wn * 64 + ni * 16 + fm;
#pragma unroll
            for (int r = 0; r < 4; ++r) {
                const int row = m0 + wm * 64 + mi * 16 + fq * 4 + r;
                const size_t off = (size_t)row * N + col;
                float c = acc[mi][ni][r] + bl[ni];
                if (RELU) c = fmaxf(c, 0.0f);
                if (RES)  c += res[off];
                if (BF16OUT) ((u16t*)Cout)[off] = f2bf(c);
                else         ((float*)Cout)[off] = c;
            }
        }
    }
}

// ---------------------------------------------------------------------------
// Fused QKV GEMM: A = h [8192][1024], W = W_qkv [3072][1024].
// Epilogue routes per col-block (block-uniform): q (scaled by QSCALE) -> qb,
// k -> kb, v -> vtb TRANSPOSED (vtb[d][token], packed 4-row ushort4 stores).
// 1D grid = (8192/256)*(3072/128) = 768, 512 threads.
// ---------------------------------------------------------------------------
__global__ __launch_bounds__(512, 2) void gemm_qkv(const u16t* __restrict__ A,
        const u16t* __restrict__ W,
        const float* __restrict__ wq_b, const float* __restrict__ wk_b,
        const float* __restrict__ wv_b,
        u16t* __restrict__ qb, u16t* __restrict__ kb, u16t* __restrict__ vtb) {
    DP_PROLOGUE_AND_LOOP(A, W, F_DIMC, 3072 / 128)
    const int which = n0 >> 10;                 // 0=q 1=k 2=v (n0 mult of 128)
    const int nb = n0 & 1023;
    const float* bias = which == 0 ? wq_b : which == 1 ? wk_b : wv_b;
    float bl[4];
#pragma unroll
    for (int ni = 0; ni < 4; ++ni) bl[ni] = bias[nb + wn * 64 + ni * 16 + fm];

    if (which == 2) {
        // v: transposed store, 4 consecutive tokens packed per ushort4
#pragma unroll
        for (int mi = 0; mi < 4; ++mi)
#pragma unroll
            for (int ni = 0; ni < 4; ++ni) {
                const int col = nb + wn * 64 + ni * 16 + fm;       // d index
                const int row0 = m0 + wm * 64 + mi * 16 + fq * 4;  // token
                ushort4 pk = make_ushort4(f2bf(acc[mi][ni][0] + bl[ni]),
                                          f2bf(acc[mi][ni][1] + bl[ni]),
                                          f2bf(acc[mi][ni][2] + bl[ni]),
                                          f2bf(acc[mi][ni][3] + bl[ni]));
                *(ushort4*)(vtb + (size_t)col * ROWS + row0) = pk;
            }
    } else {
        u16t* dst = (which == 0) ? qb : kb;
        const float sc2 = (which == 0) ? QSCALE : 1.0f;
#pragma unroll
        for (int mi = 0; mi < 4; ++mi)
#pragma unroll
            for (int ni = 0; ni < 4; ++ni) {
                const int col = nb + wn * 64 + ni * 16 + fm;
#pragma unroll
                for (int r = 0; r < 4; ++r) {
                    const int row = m0 + wm * 64 + mi * 16 + fq * 4 + r;
                    dst[(size_t)row * F_DIMC + col] = f2bf((acc[mi][ni][r] + bl[ni]) * sc2);
                }
            }
    }
}

// ---------------------------------------------------------------------------
// MFMA flash attention, v4: counted-vmcnt barriers.
// v3 used __syncthreads() twice per iter — each drains vmcnt(0), forcing the
// K(it+1) prefetch (issued at iter top) to be waited mid-iter at barrier B.
// v4: raw s_barrier with per-wave counted waits:
//   barrier B: lgkmcnt(0) + vmcnt(2) — certifies V(it) (issued end of prev
//     iter, 2 loads, oldest in queue); K(it+1) (2 newest) stays in flight
//     through the whole PV phase.
//   barrier A: lgkmcnt(0) (all waves' Vs reads landed in VGPRs) + vmcnt(0)
//     — K(it+1) is ~600 cy old here, near-free; certifies it for next
//     iter's fk reads. Then V(it+1) is issued (2 loads).
// Edge: last iter has no K prefetch -> barrier B uses vmcnt(0).
// Queue invariant at barrier B: [V(it) x2 older, K(it+1) x2 newer].
// ---------------------------------------------------------------------------
__global__ __launch_bounds__(256, 4) void attn_mfma(const u16t* __restrict__ qb,
        const u16t* __restrict__ kbuf, const u16t* __restrict__ vtb,
        u16t* __restrict__ ab) {
    __shared__ u16t Kt[2][64 * 64] __attribute__((aligned(16)));   // 16 KB
    __shared__ u16t Vs[64 * 64] __attribute__((aligned(16)));      // 8 KB
    __shared__ u16t QP[128 * 64] __attribute__((aligned(16)));     // 16 KB

    const int t = threadIdx.x;
    const int lane = t & 63;
    const int wave = t >> 6;
    const int l15 = lane & 15, q4 = lane >> 4;
    const int q0 = blockIdx.x * 128;
    const int bh = blockIdx.y;
    const int b = bh >> 4, hh = bh & 15;

    // ---- stage Q (cooperative): 1024 16B-blocks, swizzled ----
#pragma unroll
    for (int c = 0; c < 4; ++c) {
        const int beta = c * 256 + t;
        const int r = beta >> 3, o = (beta & 7) ^ (r & 7);
        ASYNC16(qb + (size_t)(b * SEQ + q0 + r) * F_DIMC + hh * 64 + o * 8,
                QP + beta * 8);
    }
    const u16t* kg = kbuf + (size_t)(b * SEQ) * F_DIMC + hh * 64;
    const u16t* vg = vtb + (size_t)(hh * 64) * ROWS + b * SEQ;

    // per-thread staging coords (loop-invariant)
    const int sb0 = t, sb1 = t + 256;
    const int sr0 = sb0 >> 3, so0 = (sb0 & 7) ^ (sr0 & 7);
    const int sr1 = sb1 >> 3, so1 = (sb1 & 7) ^ (sr1 & 7);
    const u16t* kp0 = kg + (size_t)sr0 * F_DIMC + so0 * 8;
    const u16t* kp1 = kg + (size_t)sr1 * F_DIMC + so1 * 8;
    const u16t* vp0 = vg + (size_t)sr0 * ROWS + so0 * 8;
    const u16t* vp1 = vg + (size_t)sr1 * ROWS + so1 * 8;

    // ---- pre-stage K0 -> Kt[0], V0 -> Vs ----
    ASYNC16(kp0, Kt[0] + sb0 * 8);
    ASYNC16(kp1, Kt[0] + sb1 * 8);
    ASYNC16(vp0, Vs + sb0 * 8);
    ASYNC16(vp1, Vs + sb1 * 8);
    kp0 += 64 * F_DIMC; kp1 += 64 * F_DIMC; vp0 += 64; vp1 += 64;
    __syncthreads();                       // Q + tile0 resident (once; full drain ok)

    // ---- Q B-frags (this wave's 32 rows) ----
    short8 fqr[2][2];
#pragma unroll
    for (int mt = 0; mt < 2; ++mt)
#pragma unroll
        for (int ks = 0; ks < 2; ++ks) {
            const int m = wave * 32 + mt * 16 + l15;
            const int oct = ks * 4 + q4;
            fqr[mt][ks] = *(const short8*)(QP + (m * 8 + (oct ^ (m & 7))) * 8);
        }
    // From here QP rows [wave*32, wave*32+32) are private to this wave (P).

    short8 ones;                           // bf16 1.0 broadcast (B operand)
#pragma unroll
    for (int i = 0; i < 8; ++i) ones[i] = (short)0x3F80;

    floatx4 oacc[2][4] = {};
    floatx4 lacc[2] = {};

    for (int it = 0; it < SEQ / 64; ++it) {
        // prefetch K(it+1) into the other K buffer (in flight until barrier A)
        if (it + 1 < SEQ / 64) {
            u16t* kd = Kt[(it + 1) & 1];
            ASYNC16(kp0, kd + sb0 * 8);
            ASYNC16(kp1, kd + sb1 * 8);
            kp0 += 64 * F_DIMC; kp1 += 64 * F_DIMC;
        }
        const u16t* kcur = Kt[it & 1];

        // ---- S^T = K @ Q^T : C rows = keys, cols = queries ----
        short8 fk[4][2];
#pragma unroll
        for (int nt = 0; nt < 4; ++nt)
#pragma unroll
            for (int ks = 0; ks < 2; ++ks) {
                const int kr = nt * 16 + l15;
                const int oct = ks * 4 + q4;
                fk[nt][ks] = *(const short8*)(kcur + (kr * 8 + (oct ^ (kr & 7))) * 8);
            }
        floatx4 st[2][4] = {};
#pragma unroll
        for (int mt = 0; mt < 2; ++mt)
#pragma unroll
            for (int nt = 0; nt < 4; ++nt) {
                st[mt][nt] = __builtin_amdgcn_mfma_f32_16x16x32_bf16(
                    fk[nt][0], fqr[mt][0], st[mt][nt], 0, 0, 0);
                st[mt][nt] = __builtin_amdgcn_mfma_f32_16x16x32_bf16(
                    fk[nt][1], fqr[mt][1], st[mt][nt], 0, 0, 0);
            }

        // ---- P = exp2(S^T), truncate-pack via v_perm, b64 writes (own rows)
#pragma unroll
        for (int mt = 0; mt < 2; ++mt)
#pragma unroll
            for (int nt = 0; nt < 4; ++nt) {
                const float p0 = EXP2(st[mt][nt][0]);
                const float p1 = EXP2(st[mt][nt][1]);
                const float p2 = EXP2(st[mt][nt][2]);
                const float p3 = EXP2(st[mt][nt][3]);
                const unsigned lo = __builtin_amdgcn_perm(fasu(p1), fasu(p0), 0x07060302u);
                const unsigned hi = __builtin_amdgcn_perm(fasu(p3), fasu(p2), 0x07060302u);
                const int m = wave * 32 + mt * 16 + l15;
                const int logb = nt * 2 + (q4 >> 1);       // 16B-block of k0
                *(uint2*)(QP + (m * 8 + (logb ^ (m & 7))) * 8 + (q4 & 1) * 4) =
                    make_uint2(lo, hi);
            }

        // ---- barrier B: V(it) certified; K(it+1) stays in flight ----
        asm volatile("s_waitcnt lgkmcnt(0)" ::: "memory");  // P writes done
        if (it + 1 < SEQ / 64) {
            asm volatile("s_waitcnt vmcnt(2)" ::: "memory"); // V(it) landed
        } else {
            asm volatile("s_waitcnt vmcnt(0)" ::: "memory"); // no K in queue
        }
        __builtin_amdgcn_s_barrier();

        // ---- O += P @ V ;  l += P @ 1 ----
        short8 fp[2][2], fv[4][2];
#pragma unroll
        for (int mt = 0; mt < 2; ++mt)
#pragma unroll
            for (int ks = 0; ks < 2; ++ks) {
                const int m = wave * 32 + mt * 16 + l15;
                const int oct = ks * 4 + q4;
                fp[mt][ks] = *(const short8*)(QP + (m * 8 + (oct ^ (m & 7))) * 8);
            }
#pragma unroll
        for (int nd = 0; nd < 4; ++nd)
#pragma unroll
            for (int ks = 0; ks < 2; ++ks) {
                const int d = nd * 16 + l15;
                const int oct = ks * 4 + q4;
                fv[nd][ks] = *(const short8*)(Vs + (d * 8 + (oct ^ (d & 7))) * 8);
            }
#pragma unroll
        for (int mt = 0; mt < 2; ++mt) {
#pragma unroll
            for (int nd = 0; nd < 4; ++nd) {
                oacc[mt][nd] = __builtin_amdgcn_mfma_f32_16x16x32_bf16(
                    fp[mt][0], fv[nd][0], oacc[mt][nd], 0, 0, 0);
                oacc[mt][nd] = __builtin_amdgcn_mfma_f32_16x16x32_bf16(
                    fp[mt][1], fv[nd][1], oacc[mt][nd], 0, 0, 0);
            }
            lacc[mt] = __builtin_amdgcn_mfma_f32_16x16x32_bf16(
                fp[mt][0], ones, lacc[mt], 0, 0, 0);
            lacc[mt] = __builtin_amdgcn_mfma_f32_16x16x32_bf16(
                fp[mt][1], ones, lacc[mt], 0, 0, 0);
        }

        // ---- barrier A: Vs reads landed everywhere; K(it+1) (~600cy old)
        //      certified for next iter's fk reads ----
        asm volatile("s_waitcnt lgkmcnt(0)" ::: "memory");  // my Vs/QP reads in VGPRs
        asm volatile("s_waitcnt vmcnt(0)" ::: "memory");    // K(it+1) resident (cheap)
        __builtin_amdgcn_s_barrier();
        if (it + 1 < SEQ / 64) {           // V(it+1) into Vs, in flight until B
            ASYNC16(vp0, Vs + sb0 * 8);
            ASYNC16(vp1, Vs + sb1 * 8);
            vp0 += 64; vp1 += 64;
        }
    }

    // ---- epilogue: lacc rows match oacc rows exactly; no shuffles ----
#pragma unroll
    for (int mt = 0; mt < 2; ++mt) {
        floatx4 rinv;
#pragma unroll
        for (int r = 0; r < 4; ++r) rinv[r] = 1.0f / lacc[mt][r];
#pragma unroll
        for (int nd = 0; nd < 4; ++nd)
#pragma unroll
            for (int r = 0; r < 4; ++r) {
                const int row = b * SEQ + q0 + wave * 32 + mt * 16 + q4 * 4 + r;
                const int col = hh * 64 + nd * 16 + l15;
                ab[(size_t)row * F_DIMC + col] = f2bf(oacc[mt][nd][r] * rinv[r]);
            }
    }
}

// ---------------------------------------------------------------------------
// Launcher. Workspace (u16 units, 52M u16 = 104 MB):
//   wbuf [0,12M) | h [12M,20M) | qb [20M,28M) | kb [28M,36M) | vtb [36M,44M)
//   ab [44M,52M) | ff overlays qb..vtb (32M) after attention consumed.
// ---------------------------------------------------------------------------
extern "C" void kernel_launch(void* const* d_in, const int* in_sizes, int n_in,
                              void* d_out, int out_size, void* d_ws, size_t ws_size,
                              hipStream_t stream) {
    const float* x     = (const float*)d_in[0];
    const float* ln1_w = (const float*)d_in[1];
    const float* ln1_b = (const float*)d_in[2];
    const float* wq_w  = (const float*)d_in[3];
    const float* wq_b  = (const float*)d_in[4];
    const float* wk_w  = (const float*)d_in[5];
    const float* wk_b  = (const float*)d_in[6];
    const float* wv_w  = (const float*)d_in[7];
    const float* wv_b  = (const float*)d_in[8];
    const float* fc_w  = (const float*)d_in[9];
    const float* fc_b  = (const float*)d_in[10];
    const float* ln2_w = (const float*)d_in[11];
    const float* ln2_b = (const float*)d_in[12];
    const float* fc1_w = (const float*)d_in[13];
    const float* fc1_b = (const float*)d_in[14];
    const float* fc2_w = (const float*)d_in[15];
    const float* fc2_b = (const float*)d_in[16];

    float* out = (float*)d_out;
    u16t*  ws  = (u16t*)d_ws;

    u16t* wbuf = ws;
    u16t* bwqkv = wbuf;                 // [3072][1024] fused
    u16t* bwfc = wbuf + 3 * MEG;
    u16t* bwf1 = wbuf + 4 * MEG;
    u16t* bwf2 = wbuf + 8 * MEG;
    u16t* h    = wbuf + 12 * MEG;
    u16t* qb   = h + 8 * MEG;
    u16t* kb   = qb + 8 * MEG;
    u16t* vtb  = kb + 8 * MEG;
    u16t* ab   = vtb + 8 * MEG;
    u16t* ff   = qb;                    // overlay: qb/kb/vtb dead by step 6

    const dim3 blk(256);
    const dim3 blk512(512);
    // 1D grids for deep-pipeline GEMMs: (M/256)*(N/128), all divisible by 8
    const int gQKV = (ROWS / 256) * (3072 / 128);   // 32*24 = 768
    const int gF   = (ROWS / 256) * (F_DIMC / 128); // 32*8  = 256
    const int gH   = (ROWS / 256) * (HIDC / 128);   // 32*32 = 1024

    // 0. weights -> bf16
    wconv_kernel<<<12 * MEG / 1024, blk, 0, stream>>>(wq_w, wk_w, wv_w, fc_w, fc1_w, fc2_w, wbuf);
    // 1. h = LN1(x)
    ln_kernel<<<ROWS, blk, 0, stream>>>(x, ln1_w, ln1_b, h);
    // 2. fused q (scaled), k, v^T
    gemm_qkv<<<gQKV, blk512, 0, stream>>>(h, bwqkv, wq_b, wk_b, wv_b, qb, kb, vtb);
    // 3. attention (MFMA flash v4)
    attn_mfma<<<dim3(SEQ / 128, BATCH * NH), blk, 0, stream>>>(qb, kb, vtb, ab);
    // 4. x1 = x + attn @ fc_w.T + fc_b  (fp32, into d_out)
    gemm_dp<false, true, false><<<gF, blk512, 0, stream>>>(ab, bwfc, fc_b, x, out, F_DIMC, F_DIMC);
    // 5. h = LN2(x1)
    ln_kernel<<<ROWS, blk, 0, stream>>>(out, ln2_w, ln2_b, h);
    // 6. ff = relu(h @ fc1_w.T + fc1_b)
    gemm_dp<true, false, true><<<gH, blk512, 0, stream>>>(h, bwf1, fc1_b, nullptr, ff, HIDC, F_DIMC);
    // 7. out = x1 + ff @ fc2_w.T + fc2_b
    gemm_dp<false, true, false><<<gF, blk512, 0, stream>>>(ff, bwf2, fc2_b, out, out, F_DIMC, HIDC);
}

// Round 7
// 499.964 us; speedup vs baseline: 1.1678x; 1.0280x over previous
//
#include <hip/hip_runtime.h>

// Problem constants
#define F_DIMC 1024
#define HIDC   4096
#define NH     16
#define SEQ    2048
#define BATCH  4
#define ROWS   (BATCH * SEQ)                    // 8192
#define MEG    (1u << 20)
#define QSCALE 0.18033688011112042f             // 0.125 * log2(e)

typedef unsigned short u16t;
typedef __attribute__((ext_vector_type(8))) short short8;   // 8 bf16 (4 VGPRs) — MFMA A/B frag
typedef __attribute__((ext_vector_type(4))) float floatx4;  // MFMA C/D frag
typedef __attribute__((address_space(1))) void gvoid_t;
typedef __attribute__((address_space(3))) void lvoid_t;
#define ASYNC16(g, l) __builtin_amdgcn_global_load_lds((gvoid_t*)(g), (lvoid_t*)(l), 16, 0, 0)

#if __has_builtin(__builtin_amdgcn_exp2f)
#define EXP2(x) __builtin_amdgcn_exp2f(x)       // raw v_exp_f32 (1 trans op)
#else
#define EXP2(x) exp2f(x)
#endif

__device__ __forceinline__ u16t f2bf(float f) {           // RNE float->bf16
    union { float f; unsigned u; } v; v.f = f;
    unsigned r = v.u + 0x7fffu + ((v.u >> 16) & 1u);
    return (u16t)(r >> 16);
}
__device__ __forceinline__ unsigned fasu(float f) {
    union { float f; unsigned u; } v; v.f = f; return v.u;
}

// ---------------------------------------------------------------------------
// LayerNorm: one 256-thread block per row of 1024 floats; bf16 output.
// ---------------------------------------------------------------------------
__global__ __launch_bounds__(256) void ln_kernel(const float* __restrict__ x,
                                                 const float* __restrict__ w,
                                                 const float* __restrict__ b,
                                                 u16t* __restrict__ out) {
    const int row = blockIdx.x;
    const int t = threadIdx.x;
    const float* xp = x + (size_t)row * F_DIMC;

    float4 v = *(const float4*)(xp + t * 4);
    float s  = v.x + v.y + v.z + v.w;
    float ss = v.x * v.x + v.y * v.y + v.z * v.z + v.w * v.w;
    for (int off = 32; off; off >>= 1) {
        s  += __shfl_down(s, off);
        ss += __shfl_down(ss, off);
    }
    __shared__ float red[8];
    const int wid = t >> 6, lid = t & 63;
    if (lid == 0) { red[wid] = s; red[4 + wid] = ss; }
    __syncthreads();
    if (t == 0) {
        float S  = red[0] + red[1] + red[2] + red[3];
        float SS = red[4] + red[5] + red[6] + red[7];
        float mu  = S * (1.0f / F_DIMC);
        float var = SS * (1.0f / F_DIMC) - mu * mu;
        red[0] = mu;
        red[1] = rsqrtf(var + 1e-6f);
    }
    __syncthreads();
    const float mu = red[0], rs = red[1];

    float4 wv = *(const float4*)(w + t * 4);
    float4 bv = *(const float4*)(b + t * 4);
    ushort4 o = make_ushort4(f2bf((v.x - mu) * rs * wv.x + bv.x),
                             f2bf((v.y - mu) * rs * wv.y + bv.y),
                             f2bf((v.z - mu) * rs * wv.z + bv.z),
                             f2bf((v.w - mu) * rs * wv.w + bv.w));
    *(ushort4*)(out + (size_t)row * F_DIMC + t * 4) = o;
}

// ---------------------------------------------------------------------------
// Weight conversion fp32 -> bf16, all 6 matrices in one launch.
// wbuf layout: wq[0,1M) wk[1M,2M) wv[2M,3M) fc[3M,4M) fc1[4M,8M) fc2[8M,12M)
// ---------------------------------------------------------------------------
__global__ __launch_bounds__(256) void wconv_kernel(const float* __restrict__ w0,
        const float* __restrict__ w1, const float* __restrict__ w2,
        const float* __restrict__ w3, const float* __restrict__ w4,
        const float* __restrict__ w5, u16t* __restrict__ dst) {
    const size_t e = ((size_t)blockIdx.x * 256 + threadIdx.x) * 4;
    const float* src; size_t off;
    if      (e < 1 * MEG) { src = w0; off = e; }
    else if (e < 2 * MEG) { src = w1; off = e - 1 * MEG; }
    else if (e < 3 * MEG) { src = w2; off = e - 2 * MEG; }
    else if (e < 4 * MEG) { src = w3; off = e - 3 * MEG; }
    else if (e < 8 * MEG) { src = w4; off = e - 4 * MEG; }
    else                  { src = w5; off = e - 8 * MEG; }
    float4 f = *(const float4*)(src + off);
    *(ushort4*)(dst + e) = make_ushort4(f2bf(f.x), f2bf(f.y), f2bf(f.z), f2bf(f.w));
}

// ---------------------------------------------------------------------------
// R1 GEMM core (VERIFIED — 97 µs/29% MfmaUtil/0 conflicts; 1 block/CU).
// Tile 256(M) x 128(N), BK=64, 512 threads = 8 waves as 4(M) x 2(N);
// per-wave 64x64 output = acc[4][4]. Used for N=1024 GEMMs (steps 4, 7)
// where the 256-wide tile would leave half the grid empty.
// ---------------------------------------------------------------------------
#define DP_PROLOGUE_AND_LOOP(Aq, Wq, Kdim, NBX)                                \
    __shared__ u16t As[2][256 * 64] __attribute__((aligned(16)));              \
    __shared__ u16t Ws[2][128 * 64] __attribute__((aligned(16)));              \
    const int t = threadIdx.x;                                                 \
    const int lane = t & 63;                                                   \
    const int wave = t >> 6;                                                   \
    const int wm = wave >> 1, wn = wave & 1;                                   \
    const int fm = lane & 15, fq = lane >> 4;                                  \
    const int l7 = lane & 7;                                                   \
    const int nwg = gridDim.x;                                                 \
    const int swzb = (blockIdx.x & 7) * (nwg >> 3) + (blockIdx.x >> 3);        \
    const int m0 = (swzb / (NBX)) * 256, n0 = (swzb % (NBX)) * 128;            \
    const u16t* ag[4]; const u16t* wg2[2];                                     \
    int alo[4]; int wlo[2];                                                    \
    _Pragma("unroll")                                                          \
    for (int i = 0; i < 4; ++i) {                                              \
        const int beta = i * 512 + t;                                          \
        const int r = beta >> 3, j = (beta & 7) ^ (r & 7);                     \
        ag[i] = (Aq) + (size_t)(m0 + r) * (Kdim) + j * 8;                      \
        alo[i] = beta * 8;                                                     \
    }                                                                          \
    _Pragma("unroll")                                                          \
    for (int i = 0; i < 2; ++i) {                                              \
        const int beta = i * 512 + t;                                          \
        const int r = beta >> 3, j = (beta & 7) ^ (r & 7);                     \
        wg2[i] = (Wq) + (size_t)(n0 + r) * (Kdim) + j * 8;                     \
        wlo[i] = beta * 8;                                                     \
    }                                                                          \
    int abase[2], bbase[2];                                                    \
    _Pragma("unroll")                                                          \
    for (int ks = 0; ks < 2; ++ks) {                                           \
        const int sw = (ks * 4 + fq) ^ l7;                                     \
        abase[ks] = (wm * 64 + fm) * 64 + sw * 8;                              \
        bbase[ks] = (wn * 64 + fm) * 64 + sw * 8;                              \
    }                                                                          \
    const int NT = (Kdim) / 64;                                                \
    _Pragma("unroll")                                                          \
    for (int i = 0; i < 4; ++i) ASYNC16(ag[i], &As[0][alo[i]]);                \
    _Pragma("unroll")                                                          \
    for (int i = 0; i < 2; ++i) ASYNC16(wg2[i], &Ws[0][wlo[i]]);               \
    _Pragma("unroll")                                                          \
    for (int i = 0; i < 4; ++i) ASYNC16(ag[i] + 64, &As[1][alo[i]]);           \
    _Pragma("unroll")                                                          \
    for (int i = 0; i < 2; ++i) ASYNC16(wg2[i] + 64, &Ws[1][wlo[i]]);          \
    _Pragma("unroll")                                                          \
    for (int i = 0; i < 4; ++i) ag[i] += 128;                                  \
    _Pragma("unroll")                                                          \
    for (int i = 0; i < 2; ++i) wg2[i] += 128;                                 \
    asm volatile("s_waitcnt vmcnt(6)" ::: "memory");                           \
    __builtin_amdgcn_s_barrier();                                              \
    __builtin_amdgcn_sched_barrier(0);                                         \
    floatx4 acc[4][4] = {};                                                    \
    for (int tt = 0; tt < NT; ++tt) {                                          \
        const u16t* Ab = As[tt & 1];                                           \
        const u16t* Wb = Ws[tt & 1];                                           \
        short8 fa[4], fb[4];                                                   \
        _Pragma("unroll")                                                      \
        for (int mi = 0; mi < 4; ++mi)                                         \
            fa[mi] = *(const short8*)(Ab + abase[0] + mi * 1024);              \
        _Pragma("unroll")                                                      \
        for (int ni = 0; ni < 4; ++ni)                                         \
            fb[ni] = *(const short8*)(Wb + bbase[0] + ni * 1024);              \
        __builtin_amdgcn_s_setprio(1);                                         \
        _Pragma("unroll")                                                      \
        for (int mi = 0; mi < 4; ++mi)                                         \
            _Pragma("unroll")                                                  \
            for (int ni = 0; ni < 4; ++ni)                                     \
                acc[mi][ni] = __builtin_amdgcn_mfma_f32_16x16x32_bf16(         \
                    fa[mi], fb[ni], acc[mi][ni], 0, 0, 0);                     \
        __builtin_amdgcn_s_setprio(0);                                         \
        short8 fa1[4], fb1[4];                                                 \
        _Pragma("unroll")                                                      \
        for (int mi = 0; mi < 4; ++mi)                                         \
            fa1[mi] = *(const short8*)(Ab + abase[1] + mi * 1024);             \
        _Pragma("unroll")                                                      \
        for (int ni = 0; ni < 4; ++ni)                                         \
            fb1[ni] = *(const short8*)(Wb + bbase[1] + ni * 1024);             \
        asm volatile("s_waitcnt lgkmcnt(0)" ::: "memory");                     \
        __builtin_amdgcn_s_barrier();                                          \
        __builtin_amdgcn_sched_barrier(0);                                     \
        if (tt + 2 < NT) {                                                     \
            const int pb = tt & 1;                                             \
            _Pragma("unroll")                                                  \
            for (int i = 0; i < 4; ++i) {                                      \
                ASYNC16(ag[i], &As[pb][alo[i]]); ag[i] += 64;                  \
            }                                                                  \
            _Pragma("unroll")                                                  \
            for (int i = 0; i < 2; ++i) {                                      \
                ASYNC16(wg2[i], &Ws[pb][wlo[i]]); wg2[i] += 64;                \
            }                                                                  \
            asm volatile("s_waitcnt vmcnt(6)" ::: "memory");                   \
        } else {                                                               \
            asm volatile("s_waitcnt vmcnt(0)" ::: "memory");                   \
        }                                                                      \
        __builtin_amdgcn_s_barrier();                                          \
        __builtin_amdgcn_sched_barrier(0);                                     \
        __builtin_amdgcn_s_setprio(1);                                         \
        _Pragma("unroll")                                                      \
        for (int mi = 0; mi < 4; ++mi)                                         \
            _Pragma("unroll")                                                  \
            for (int ni = 0; ni < 4; ++ni)                                     \
                acc[mi][ni] = __builtin_amdgcn_mfma_f32_16x16x32_bf16(         \
                    fa1[mi], fb1[ni], acc[mi][ni], 0, 0, 0);                   \
        __builtin_amdgcn_s_setprio(0);                                         \
    }

// ---------------------------------------------------------------------------
// WIDE GEMM core: identical 2-phase counted-vmcnt skeleton, tile 256x256,
// 8 waves as 2(M wr) x 4(N wc), per-wave 128x64 output = acc[8][4].
// Rationale (R6 counters): R1 core is LDS-read-bound — 128 KB of frag reads
// per 256x128x64 tile (0.031 B/FLOP > 0.025 threshold at 85 B/cy).
// Per-wave 128x64 reads 24 frags/64 MFMA -> 0.023 B/FLOP (MFMA-bound).
// Same conflict-free 128B-row XOR (row&7 == fm&7, mi/ni-invariant).
// LDS = A[2][256][64] + B[2][256][64] = 128 KB; 1 block/CU (same as R1).
// Staging = 8 loads/tile -> counted vmcnt(8). Used for N>=3072 (step 6, QKV).
// ---------------------------------------------------------------------------
#define DPW_PROLOGUE_AND_LOOP(Aq, Wq, Kdim, NBX)                               \
    __shared__ u16t As[2][256 * 64] __attribute__((aligned(16)));              \
    __shared__ u16t Bs[2][256 * 64] __attribute__((aligned(16)));              \
    const int t = threadIdx.x;                                                 \
    const int lane = t & 63;                                                   \
    const int wave = t >> 6;                                                   \
    const int wr = wave >> 2, wc = wave & 3;                                   \
    const int fm = lane & 15, fq = lane >> 4;                                  \
    const int l7 = lane & 7;                                                   \
    const int nwg = gridDim.x;                                                 \
    const int swzb = (blockIdx.x & 7) * (nwg >> 3) + (blockIdx.x >> 3);        \
    const int m0 = (swzb / (NBX)) * 256, n0 = (swzb % (NBX)) * 256;            \
    const u16t* ag[4]; const u16t* bg[4];                                      \
    int alo[4]; int blo[4];                                                    \
    _Pragma("unroll")                                                          \
    for (int i = 0; i < 4; ++i) {                                              \
        const int beta = i * 512 + t;                                          \
        const int r = beta >> 3, j = (beta & 7) ^ (r & 7);                     \
        ag[i] = (Aq) + (size_t)(m0 + r) * (Kdim) + j * 8;                      \
        bg[i] = (Wq) + (size_t)(n0 + r) * (Kdim) + j * 8;                      \
        alo[i] = beta * 8; blo[i] = beta * 8;                                  \
    }                                                                          \
    int abase[2], bbase[2];                                                    \
    _Pragma("unroll")                                                          \
    for (int ks = 0; ks < 2; ++ks) {                                           \
        const int sw = (ks * 4 + fq) ^ l7;                                     \
        abase[ks] = (wr * 128 + fm) * 64 + sw * 8;                             \
        bbase[ks] = (wc * 64 + fm) * 64 + sw * 8;                              \
    }                                                                          \
    const int NT = (Kdim) / 64;                                                \
    _Pragma("unroll")                                                          \
    for (int i = 0; i < 4; ++i) ASYNC16(ag[i], &As[0][alo[i]]);                \
    _Pragma("unroll")                                                          \
    for (int i = 0; i < 4; ++i) ASYNC16(bg[i], &Bs[0][blo[i]]);                \
    _Pragma("unroll")                                                          \
    for (int i = 0; i < 4; ++i) { ASYNC16(ag[i] + 64, &As[1][alo[i]]); ag[i] += 128; } \
    _Pragma("unroll")                                                          \
    for (int i = 0; i < 4; ++i) { ASYNC16(bg[i] + 64, &Bs[1][blo[i]]); bg[i] += 128; } \
    asm volatile("s_waitcnt vmcnt(8)" ::: "memory");   /* tile0 landed */      \
    __builtin_amdgcn_s_barrier();                                              \
    __builtin_amdgcn_sched_barrier(0);                                         \
    floatx4 acc[8][4] = {};                                                    \
    for (int tt = 0; tt < NT; ++tt) {                                          \
        const u16t* Ab = As[tt & 1];                                           \
        const u16t* Bb = Bs[tt & 1];                                           \
        /* ---- slice 0: read frags, MFMA ---- */                              \
        short8 fa[8], fb[4];                                                   \
        _Pragma("unroll")                                                      \
        for (int mi = 0; mi < 8; ++mi)                                         \
            fa[mi] = *(const short8*)(Ab + abase[0] + mi * 1024);              \
        _Pragma("unroll")                                                      \
        for (int ni = 0; ni < 4; ++ni)                                         \
            fb[ni] = *(const short8*)(Bb + bbase[0] + ni * 1024);              \
        __builtin_amdgcn_s_setprio(1);                                         \
        _Pragma("unroll")                                                      \
        for (int mi = 0; mi < 8; ++mi)                                         \
            _Pragma("unroll")                                                  \
            for (int ni = 0; ni < 4; ++ni)                                     \
                acc[mi][ni] = __builtin_amdgcn_mfma_f32_16x16x32_bf16(         \
                    fa[mi], fb[ni], acc[mi][ni], 0, 0, 0);                     \
        __builtin_amdgcn_s_setprio(0);                                         \
        /* ---- slice 1 reads (overlap slice-0 MFMA drain) ---- */             \
        short8 fa1[8], fb1[4];                                                 \
        _Pragma("unroll")                                                      \
        for (int mi = 0; mi < 8; ++mi)                                         \
            fa1[mi] = *(const short8*)(Ab + abase[1] + mi * 1024);             \
        _Pragma("unroll")                                                      \
        for (int ni = 0; ni < 4; ++ni)                                         \
            fb1[ni] = *(const short8*)(Bb + bbase[1] + ni * 1024);             \
        asm volatile("s_waitcnt lgkmcnt(0)" ::: "memory");                     \
        __builtin_amdgcn_s_barrier();                                          \
        __builtin_amdgcn_sched_barrier(0);                                     \
        if (tt + 2 < NT) {                                                     \
            const int pb = tt & 1;                                             \
            _Pragma("unroll")                                                  \
            for (int i = 0; i < 4; ++i) {                                      \
                ASYNC16(ag[i], &As[pb][alo[i]]); ag[i] += 64;                  \
            }                                                                  \
            _Pragma("unroll")                                                  \
            for (int i = 0; i < 4; ++i) {                                      \
                ASYNC16(bg[i], &Bs[pb][blo[i]]); bg[i] += 64;                  \
            }                                                                  \
            asm volatile("s_waitcnt vmcnt(8)" ::: "memory");                   \
        } else {                                                               \
            asm volatile("s_waitcnt vmcnt(0)" ::: "memory");                   \
        }                                                                      \
        __builtin_amdgcn_s_barrier();                                          \
        __builtin_amdgcn_sched_barrier(0);                                     \
        /* ---- slice 1 MFMA (overlaps next tile's slice-0 reads) ---- */      \
        __builtin_amdgcn_s_setprio(1);                                         \
        _Pragma("unroll")                                                      \
        for (int mi = 0; mi < 8; ++mi)                                         \
            _Pragma("unroll")                                                  \
            for (int ni = 0; ni < 4; ++ni)                                     \
                acc[mi][ni] = __builtin_amdgcn_mfma_f32_16x16x32_bf16(         \
                    fa1[mi], fb1[ni], acc[mi][ni], 0, 0, 0);                   \
        __builtin_amdgcn_s_setprio(0);                                         \
    }

// ---------------------------------------------------------------------------
// Generic bf16 MFMA GEMM (R1 core): C = A @ W^T + bias (+ReLU)(+res)
// 1D grid = (M/256)*(N/128), 512 threads. Used for N=1024 (steps 4, 7).
// ---------------------------------------------------------------------------
template <bool RELU, bool RES, bool BF16OUT>
__global__ __launch_bounds__(512, 2) void gemm_dp(const u16t* __restrict__ A,
                                                  const u16t* __restrict__ W,
                                                  const float* __restrict__ bias,
                                                  const float* res, void* Cout,
                                                  int N, int K) {
    DP_PROLOGUE_AND_LOOP(A, W, K, N / 128)
    float bl[4];
#pragma unroll
    for (int ni = 0; ni < 4; ++ni) bl[ni] = bias[n0 + wn * 64 + ni * 16 + fm];
#pragma unroll
    for (int mi = 0; mi < 4; ++mi) {
#pragma unroll
        for (int ni = 0; ni < 4; ++ni) {
            const int col = n0 + wn * 64 + ni * 16 + fm;
#pragma unroll
            for (int r = 0; r < 4; ++r) {
                const int row = m0 + wm * 64 + mi * 16 + fq * 4 + r;
                const size_t off = (size_t)row * N + col;
                float c = acc[mi][ni][r] + bl[ni];
                if (RELU) c = fmaxf(c, 0.0f);
                if (RES)  c += res[off];
                if (BF16OUT) ((u16t*)Cout)[off] = f2bf(c);
                else         ((float*)Cout)[off] = c;
            }
        }
    }
}

// ---------------------------------------------------------------------------
// Wide GEMM (256x256 core): C = A @ W^T + bias (+ReLU)(+res)
// 1D grid = (M/256)*(N/256), 512 threads. Used for step 6 (N=4096).
// ---------------------------------------------------------------------------
template <bool RELU, bool RES, bool BF16OUT>
__global__ __launch_bounds__(512, 2) void gemm_dpw(const u16t* __restrict__ A,
                                                   const u16t* __restrict__ W,
                                                   const float* __restrict__ bias,
                                                   const float* res, void* Cout,
                                                   int N, int K) {
    DPW_PROLOGUE_AND_LOOP(A, W, K, N / 256)
    float bl[4];
#pragma unroll
    for (int ni = 0; ni < 4; ++ni) bl[ni] = bias[n0 + wc * 64 + ni * 16 + fm];
#pragma unroll
    for (int mi = 0; mi < 8; ++mi) {
#pragma unroll
        for (int ni = 0; ni < 4; ++ni) {
            const int col = n0 + wc * 64 + ni * 16 + fm;
#pragma unroll
            for (int r = 0; r < 4; ++r) {
                const int row = m0 + wr * 128 + mi * 16 + fq * 4 + r;
                const size_t off = (size_t)row * N + col;
                float c = acc[mi][ni][r] + bl[ni];
                if (RELU) c = fmaxf(c, 0.0f);
                if (RES)  c += res[off];
                if (BF16OUT) ((u16t*)Cout)[off] = f2bf(c);
                else         ((float*)Cout)[off] = c;
            }
        }
    }
}

// ---------------------------------------------------------------------------
// Fused QKV GEMM (256x256 core): A = h [8192][1024], W = W_qkv [3072][1024].
// n0 multiple of 256 never straddles the q/k/v 1024-boundaries. Routes:
// q (scaled) -> qb, k -> kb, v -> vtb TRANSPOSED (vtb[d][token]).
// 1D grid = 32*(3072/256) = 384, 512 threads.
// ---------------------------------------------------------------------------
__global__ __launch_bounds__(512, 2) void gemm_qkv(const u16t* __restrict__ A,
        const u16t* __restrict__ W,
        const float* __restrict__ wq_b, const float* __restrict__ wk_b,
        const float* __restrict__ wv_b,
        u16t* __restrict__ qb, u16t* __restrict__ kb, u16t* __restrict__ vtb) {
    DPW_PROLOGUE_AND_LOOP(A, W, F_DIMC, 3072 / 256)
    const int which = n0 >> 10;                 // 0=q 1=k 2=v
    const int nb = n0 & 1023;
    const float* bias = which == 0 ? wq_b : which == 1 ? wk_b : wv_b;
    float bl[4];
#pragma unroll
    for (int ni = 0; ni < 4; ++ni) bl[ni] = bias[nb + wc * 64 + ni * 16 + fm];

    if (which == 2) {
        // v: transposed store, 4 consecutive tokens packed per ushort4
#pragma unroll
        for (int mi = 0; mi < 8; ++mi)
#pragma unroll
            for (int ni = 0; ni < 4; ++ni) {
                const int col = nb + wc * 64 + ni * 16 + fm;        // d index
                const int row0 = m0 + wr * 128 + mi * 16 + fq * 4;  // token
                ushort4 pk = make_ushort4(f2bf(acc[mi][ni][0] + bl[ni]),
                                          f2bf(acc[mi][ni][1] + bl[ni]),
                                          f2bf(acc[mi][ni][2] + bl[ni]),
                                          f2bf(acc[mi][ni][3] + bl[ni]));
                *(ushort4*)(vtb + (size_t)col * ROWS + row0) = pk;
            }
    } else {
        u16t* dst = (which == 0) ? qb : kb;
        const float sc2 = (which == 0) ? QSCALE : 1.0f;
#pragma unroll
        for (int mi = 0; mi < 8; ++mi)
#pragma unroll
            for (int ni = 0; ni < 4; ++ni) {
                const int col = nb + wc * 64 + ni * 16 + fm;
#pragma unroll
                for (int r = 0; r < 4; ++r) {
                    const int row = m0 + wr * 128 + mi * 16 + fq * 4 + r;
                    dst[(size_t)row * F_DIMC + col] = f2bf((acc[mi][ni][r] + bl[ni]) * sc2);
                }
            }
    }
}

// ---------------------------------------------------------------------------
// MFMA flash attention, v4 (unchanged from R6): counted-vmcnt barriers.
// ---------------------------------------------------------------------------
__global__ __launch_bounds__(256, 4) void attn_mfma(const u16t* __restrict__ qb,
        const u16t* __restrict__ kbuf, const u16t* __restrict__ vtb,
        u16t* __restrict__ ab) {
    __shared__ u16t Kt[2][64 * 64] __attribute__((aligned(16)));   // 16 KB
    __shared__ u16t Vs[64 * 64] __attribute__((aligned(16)));      // 8 KB
    __shared__ u16t QP[128 * 64] __attribute__((aligned(16)));     // 16 KB

    const int t = threadIdx.x;
    const int lane = t & 63;
    const int wave = t >> 6;
    const int l15 = lane & 15, q4 = lane >> 4;
    const int q0 = blockIdx.x * 128;
    const int bh = blockIdx.y;
    const int b = bh >> 4, hh = bh & 15;

    // ---- stage Q (cooperative): 1024 16B-blocks, swizzled ----
#pragma unroll
    for (int c = 0; c < 4; ++c) {
        const int beta = c * 256 + t;
        const int r = beta >> 3, o = (beta & 7) ^ (r & 7);
        ASYNC16(qb + (size_t)(b * SEQ + q0 + r) * F_DIMC + hh * 64 + o * 8,
                QP + beta * 8);
    }
    const u16t* kg = kbuf + (size_t)(b * SEQ) * F_DIMC + hh * 64;
    const u16t* vg = vtb + (size_t)(hh * 64) * ROWS + b * SEQ;

    // per-thread staging coords (loop-invariant)
    const int sb0 = t, sb1 = t + 256;
    const int sr0 = sb0 >> 3, so0 = (sb0 & 7) ^ (sr0 & 7);
    const int sr1 = sb1 >> 3, so1 = (sb1 & 7) ^ (sr1 & 7);
    const u16t* kp0 = kg + (size_t)sr0 * F_DIMC + so0 * 8;
    const u16t* kp1 = kg + (size_t)sr1 * F_DIMC + so1 * 8;
    const u16t* vp0 = vg + (size_t)sr0 * ROWS + so0 * 8;
    const u16t* vp1 = vg + (size_t)sr1 * ROWS + so1 * 8;

    // ---- pre-stage K0 -> Kt[0], V0 -> Vs ----
    ASYNC16(kp0, Kt[0] + sb0 * 8);
    ASYNC16(kp1, Kt[0] + sb1 * 8);
    ASYNC16(vp0, Vs + sb0 * 8);
    ASYNC16(vp1, Vs + sb1 * 8);
    kp0 += 64 * F_DIMC; kp1 += 64 * F_DIMC; vp0 += 64; vp1 += 64;
    __syncthreads();                       // Q + tile0 resident (once; full drain ok)

    // ---- Q B-frags (this wave's 32 rows) ----
    short8 fqr[2][2];
#pragma unroll
    for (int mt = 0; mt < 2; ++mt)
#pragma unroll
        for (int ks = 0; ks < 2; ++ks) {
            const int m = wave * 32 + mt * 16 + l15;
            const int oct = ks * 4 + q4;
            fqr[mt][ks] = *(const short8*)(QP + (m * 8 + (oct ^ (m & 7))) * 8);
        }
    // From here QP rows [wave*32, wave*32+32) are private to this wave (P).

    short8 ones;                           // bf16 1.0 broadcast (B operand)
#pragma unroll
    for (int i = 0; i < 8; ++i) ones[i] = (short)0x3F80;

    floatx4 oacc[2][4] = {};
    floatx4 lacc[2] = {};

    for (int it = 0; it < SEQ / 64; ++it) {
        // prefetch K(it+1) into the other K buffer (in flight until barrier A)
        if (it + 1 < SEQ / 64) {
            u16t* kd = Kt[(it + 1) & 1];
            ASYNC16(kp0, kd + sb0 * 8);
            ASYNC16(kp1, kd + sb1 * 8);
            kp0 += 64 * F_DIMC; kp1 += 64 * F_DIMC;
        }
        const u16t* kcur = Kt[it & 1];

        // ---- S^T = K @ Q^T : C rows = keys, cols = queries ----
        short8 fk[4][2];
#pragma unroll
        for (int nt = 0; nt < 4; ++nt)
#pragma unroll
            for (int ks = 0; ks < 2; ++ks) {
                const int kr = nt * 16 + l15;
                const int oct = ks * 4 + q4;
                fk[nt][ks] = *(const short8*)(kcur + (kr * 8 + (oct ^ (kr & 7))) * 8);
            }
        floatx4 st[2][4] = {};
#pragma unroll
        for (int mt = 0; mt < 2; ++mt)
#pragma unroll
            for (int nt = 0; nt < 4; ++nt) {
                st[mt][nt] = __builtin_amdgcn_mfma_f32_16x16x32_bf16(
                    fk[nt][0], fqr[mt][0], st[mt][nt], 0, 0, 0);
                st[mt][nt] = __builtin_amdgcn_mfma_f32_16x16x32_bf16(
                    fk[nt][1], fqr[mt][1], st[mt][nt], 0, 0, 0);
            }

        // ---- P = exp2(S^T), truncate-pack via v_perm, b64 writes (own rows)
#pragma unroll
        for (int mt = 0; mt < 2; ++mt)
#pragma unroll
            for (int nt = 0; nt < 4; ++nt) {
                const float p0 = EXP2(st[mt][nt][0]);
                const float p1 = EXP2(st[mt][nt][1]);
                const float p2 = EXP2(st[mt][nt][2]);
                const float p3 = EXP2(st[mt][nt][3]);
                const unsigned lo = __builtin_amdgcn_perm(fasu(p1), fasu(p0), 0x07060302u);
                const unsigned hi = __builtin_amdgcn_perm(fasu(p3), fasu(p2), 0x07060302u);
                const int m = wave * 32 + mt * 16 + l15;
                const int logb = nt * 2 + (q4 >> 1);       // 16B-block of k0
                *(uint2*)(QP + (m * 8 + (logb ^ (m & 7))) * 8 + (q4 & 1) * 4) =
                    make_uint2(lo, hi);
            }

        // ---- barrier B: V(it) certified; K(it+1) stays in flight ----
        asm volatile("s_waitcnt lgkmcnt(0)" ::: "memory");  // P writes done
        if (it + 1 < SEQ / 64) {
            asm volatile("s_waitcnt vmcnt(2)" ::: "memory"); // V(it) landed
        } else {
            asm volatile("s_waitcnt vmcnt(0)" ::: "memory"); // no K in queue
        }
        __builtin_amdgcn_s_barrier();

        // ---- O += P @ V ;  l += P @ 1 ----
        short8 fp[2][2], fv[4][2];
#pragma unroll
        for (int mt = 0; mt < 2; ++mt)
#pragma unroll
            for (int ks = 0; ks < 2; ++ks) {
                const int m = wave * 32 + mt * 16 + l15;
                const int oct = ks * 4 + q4;
                fp[mt][ks] = *(const short8*)(QP + (m * 8 + (oct ^ (m & 7))) * 8);
            }
#pragma unroll
        for (int nd = 0; nd < 4; ++nd)
#pragma unroll
            for (int ks = 0; ks < 2; ++ks) {
                const int d = nd * 16 + l15;
                const int oct = ks * 4 + q4;
                fv[nd][ks] = *(const short8*)(Vs + (d * 8 + (oct ^ (d & 7))) * 8);
            }
#pragma unroll
        for (int mt = 0; mt < 2; ++mt) {
#pragma unroll
            for (int nd = 0; nd < 4; ++nd) {
                oacc[mt][nd] = __builtin_amdgcn_mfma_f32_16x16x32_bf16(
                    fp[mt][0], fv[nd][0], oacc[mt][nd], 0, 0, 0);
                oacc[mt][nd] = __builtin_amdgcn_mfma_f32_16x16x32_bf16(
                    fp[mt][1], fv[nd][1], oacc[mt][nd], 0, 0, 0);
            }
            lacc[mt] = __builtin_amdgcn_mfma_f32_16x16x32_bf16(
                fp[mt][0], ones, lacc[mt], 0, 0, 0);
            lacc[mt] = __builtin_amdgcn_mfma_f32_16x16x32_bf16(
                fp[mt][1], ones, lacc[mt], 0, 0, 0);
        }

        // ---- barrier A: Vs reads landed everywhere; K(it+1) certified ----
        asm volatile("s_waitcnt lgkmcnt(0)" ::: "memory");
        asm volatile("s_waitcnt vmcnt(0)" ::: "memory");
        __builtin_amdgcn_s_barrier();
        if (it + 1 < SEQ / 64) {           // V(it+1) into Vs, in flight until B
            ASYNC16(vp0, Vs + sb0 * 8);
            ASYNC16(vp1, Vs + sb1 * 8);
            vp0 += 64; vp1 += 64;
        }
    }

    // ---- epilogue: lacc rows match oacc rows exactly; no shuffles ----
#pragma unroll
    for (int mt = 0; mt < 2; ++mt) {
        floatx4 rinv;
#pragma unroll
        for (int r = 0; r < 4; ++r) rinv[r] = 1.0f / lacc[mt][r];
#pragma unroll
        for (int nd = 0; nd < 4; ++nd)
#pragma unroll
            for (int r = 0; r < 4; ++r) {
                const int row = b * SEQ + q0 + wave * 32 + mt * 16 + q4 * 4 + r;
                const int col = hh * 64 + nd * 16 + l15;
                ab[(size_t)row * F_DIMC + col] = f2bf(oacc[mt][nd][r] * rinv[r]);
            }
    }
}

// ---------------------------------------------------------------------------
// Launcher. Workspace (u16 units, 52M u16 = 104 MB):
//   wbuf [0,12M) | h [12M,20M) | qb [20M,28M) | kb [28M,36M) | vtb [36M,44M)
//   ab [44M,52M) | ff overlays qb..vtb (32M) after attention consumed.
// ---------------------------------------------------------------------------
extern "C" void kernel_launch(void* const* d_in, const int* in_sizes, int n_in,
                              void* d_out, int out_size, void* d_ws, size_t ws_size,
                              hipStream_t stream) {
    const float* x     = (const float*)d_in[0];
    const float* ln1_w = (const float*)d_in[1];
    const float* ln1_b = (const float*)d_in[2];
    const float* wq_w  = (const float*)d_in[3];
    const float* wq_b  = (const float*)d_in[4];
    const float* wk_w  = (const float*)d_in[5];
    const float* wk_b  = (const float*)d_in[6];
    const float* wv_w  = (const float*)d_in[7];
    const float* wv_b  = (const float*)d_in[8];
    const float* fc_w  = (const float*)d_in[9];
    const float* fc_b  = (const float*)d_in[10];
    const float* ln2_w = (const float*)d_in[11];
    const float* ln2_b = (const float*)d_in[12];
    const float* fc1_w = (const float*)d_in[13];
    const float* fc1_b = (const float*)d_in[14];
    const float* fc2_w = (const float*)d_in[15];
    const float* fc2_b = (const float*)d_in[16];

    float* out = (float*)d_out;
    u16t*  ws  = (u16t*)d_ws;

    u16t* wbuf = ws;
    u16t* bwqkv = wbuf;                 // [3072][1024] fused
    u16t* bwfc = wbuf + 3 * MEG;
    u16t* bwf1 = wbuf + 4 * MEG;
    u16t* bwf2 = wbuf + 8 * MEG;
    u16t* h    = wbuf + 12 * MEG;
    u16t* qb   = h + 8 * MEG;
    u16t* kb   = qb + 8 * MEG;
    u16t* vtb  = kb + 8 * MEG;
    u16t* ab   = vtb + 8 * MEG;
    u16t* ff   = qb;                    // overlay: qb/kb/vtb dead by step 6

    const dim3 blk(256);
    const dim3 blk512(512);
    // 1D grids; all divisible by 8 (XCD swizzle bijective)
    const int gQKV = (ROWS / 256) * (3072 / 256);   // 32*12 = 384  (wide core)
    const int gF   = (ROWS / 256) * (F_DIMC / 128); // 32*8  = 256  (R1 core)
    const int gH   = (ROWS / 256) * (HIDC / 256);   // 32*16 = 512  (wide core)

    // 0. weights -> bf16
    wconv_kernel<<<12 * MEG / 1024, blk, 0, stream>>>(wq_w, wk_w, wv_w, fc_w, fc1_w, fc2_w, wbuf);
    // 1. h = LN1(x)
    ln_kernel<<<ROWS, blk, 0, stream>>>(x, ln1_w, ln1_b, h);
    // 2. fused q (scaled), k, v^T  (wide core)
    gemm_qkv<<<gQKV, blk512, 0, stream>>>(h, bwqkv, wq_b, wk_b, wv_b, qb, kb, vtb);
    // 3. attention (MFMA flash v4)
    attn_mfma<<<dim3(SEQ / 128, BATCH * NH), blk, 0, stream>>>(qb, kb, vtb, ab);
    // 4. x1 = x + attn @ fc_w.T + fc_b  (fp32, into d_out)  (R1 core, N=1024)
    gemm_dp<false, true, false><<<gF, blk512, 0, stream>>>(ab, bwfc, fc_b, x, out, F_DIMC, F_DIMC);
    // 5. h = LN2(x1)
    ln_kernel<<<ROWS, blk, 0, stream>>>(out, ln2_w, ln2_b, h);
    // 6. ff = relu(h @ fc1_w.T + fc1_b)  (wide core, N=4096)
    gemm_dpw<true, false, true><<<gH, blk512, 0, stream>>>(h, bwf1, fc1_b, nullptr, ff, HIDC, F_DIMC);
    // 7. out = x1 + ff @ fc2_w.T + fc2_b  (R1 core, N=1024)
    gemm_dp<false, true, false><<<gF, blk512, 0, stream>>>(ff, bwf2, fc2_b, out, out, F_DIMC, HIDC);
}